// Round 12
// baseline (1167.288 us; speedup 1.0000x reference)
//
#include <hip/hip_runtime.h>
#include <hip/hip_cooperative_groups.h>
#include <math.h>

namespace cg = cooperative_groups;

constexpr int kN = 4096;
constexpr int kM = 4100;
constexpr int kD = 256;
constexpr int ROWCAP = 64;
constexpr int COLCAP = 64;
constexpr int EB_CHUNKS = 64;
constexpr float kLnEps = 1e-5f;
constexpr float kScale = 0.17677669529663687f; // 1/sqrt(32)

typedef short v8bf __attribute__((ext_vector_type(8)));
typedef float v4f  __attribute__((ext_vector_type(4)));

__device__ __forceinline__ float waveSum(float v) {
#pragma unroll
  for (int m = 32; m >= 1; m >>= 1) v += __shfl_xor(v, m);
  return v;
}
__device__ __forceinline__ float waveMax(float v) {
#pragma unroll
  for (int m = 32; m >= 1; m >>= 1) v = fmaxf(v, __shfl_xor(v, m));
  return v;
}
__device__ __forceinline__ float blockSum256(float v, float* sh) {
  v = waveSum(v);
  int lane = threadIdx.x & 63, w = threadIdx.x >> 6;
  __syncthreads();
  if (lane == 0) sh[w] = v;
  __syncthreads();
  return sh[0] + sh[1] + sh[2] + sh[3];
}
__device__ __forceinline__ short f2bf(float x) {
  unsigned u = __float_as_uint(x);
  unsigned r = (u + 0x7fffu + ((u >> 16) & 1u)) >> 16;
  return (short)r;
}
__device__ __forceinline__ float bf2f(short h) {
  return __uint_as_float(((unsigned)(unsigned short)h) << 16);
}
__device__ __forceinline__ int fragOff(int n, int k) {
  return ((n >> 4) << 12) + ((k >> 5) << 9) + (((k >> 3) & 3) << 7) + ((n & 15) << 3) + (k & 7);
}

// ======================= R10 fallback kernels (verbatim) =======================
__global__ __launch_bounds__(256) void k_build_csr(
    const float* __restrict__ H, int* __restrict__ row_cnt, int* __restrict__ row_idx,
    int* __restrict__ col_cnt, int* __restrict__ col_idx, float* __restrict__ col_val,
    float* __restrict__ Htail) {
  int n = (blockIdx.x * blockDim.x + threadIdx.x) >> 6;
  int lane = threadIdx.x & 63;
  const float* hrow = H + (size_t)n * kM;
  float4 v[16];
#pragma unroll
  for (int c = 0; c < 16; ++c) v[c] = *(const float4*)&hrow[c * 256 + lane * 4];
  float tv = (lane < 4) ? hrow[4096 + lane] : 0.0f;
  if (lane < 4) Htail[lane * kN + n] = tv;
  unsigned long long below = (1ull << lane) - 1ull;
  int cnt = 0;
#pragma unroll
  for (int c = 0; c < 16; ++c) {
    int mbase = c * 256 + lane * 4;
    float vv[4] = {v[c].x, v[c].y, v[c].z, v[c].w};
    unsigned long long bal[4];
#pragma unroll
    for (int j = 0; j < 4; ++j) bal[j] = __ballot(vv[j] != 0.0f);
    int pre = 0, tot = 0;
#pragma unroll
    for (int j = 0; j < 4; ++j) { pre += __popcll(bal[j] & below); tot += __popcll(bal[j]); }
    int local = 0;
#pragma unroll
    for (int j = 0; j < 4; ++j) {
      if (vv[j] != 0.0f) {
        int m = mbase + j;
        int pos = cnt + pre + local;
        if (pos < ROWCAP) row_idx[n * ROWCAP + pos] = m;
        int pc = atomicAdd(&col_cnt[m], 1);
        if (pc < COLCAP) { col_idx[m * COLCAP + pc] = n; col_val[m * COLCAP + pc] = vv[j]; }
        local++;
      }
    }
    cnt += tot;
  }
  unsigned long long bal = __ballot(tv != 0.0f);
  if (tv != 0.0f) {
    int pos = cnt + __popcll(bal & below);
    if (pos < ROWCAP) row_idx[n * ROWCAP + pos] = 4096 + lane;
  }
  cnt += __popcll(bal);
  if (lane == 0) row_cnt[n] = cnt < ROWCAP ? cnt : ROWCAP;
}

__global__ __launch_bounds__(256) void k_sort_csc(
    int* __restrict__ col_cnt, int* __restrict__ col_idx, float* __restrict__ col_val,
    float* __restrict__ deg) {
  int c = (blockIdx.x * blockDim.x + threadIdx.x) >> 6;
  int lane = threadIdx.x & 63;
  if (c < 4 && lane == 0) deg[kN + c] = 0.0f;
  int cnt = col_cnt[c]; if (cnt > COLCAP) cnt = COLCAP;
  int iv = 0x7fffffff; float vv = 0.0f;
  if (lane < cnt) { iv = col_idx[c * COLCAP + lane]; vv = col_val[c * COLCAP + lane]; }
  float dsum = waveSum(vv);
  int rank = 0;
  for (int j = 0; j < 64; ++j) {
    int ivj = __shfl(iv, j);
    if (ivj < iv) rank++;
  }
  if (lane < cnt) { col_idx[c * COLCAP + rank] = iv; col_val[c * COLCAP + rank] = vv; }
  if (lane == 0) { deg[c] = dsum; col_cnt[c] = cnt; }
}

struct WPtrs { const float* w[8]; };
__global__ __launch_bounds__(256) void k_wsplit(
    WPtrs wp, short* __restrict__ hi, short* __restrict__ lo) {
  int mat = blockIdx.y;
  int i = blockIdx.x * 256 + threadIdx.x;
  int out = i >> 8, k = i & 255;
  float v = wp.w[mat][i];
  short h = f2bf(v);
  size_t base = (size_t)mat * 65536 + fragOff(out, k);
  hi[base] = h;
  lo[base] = f2bf(v - bf2f(h));
}

__global__ __launch_bounds__(256) void k_pre(
    const float* __restrict__ X, const float* __restrict__ Htail,
    const int* __restrict__ col_cnt, const int* __restrict__ col_idx,
    const float* __restrict__ col_val, float* __restrict__ deg,
    const float* __restrict__ g, const float* __restrict__ b,
    short* __restrict__ Xnh, short* __restrict__ Xnl,
    short* __restrict__ Enh, short* __restrict__ Enl,
    float* __restrict__ ebpart, int add_deg) {
  __shared__ int sidx[4][COLCAP];
  __shared__ float sval[4][COLCAP];
  int bid = blockIdx.x, t = threadIdx.x;
  int wq = t >> 6, lane = t & 63;
  if (bid < 256) {
    __shared__ float hv[64];
    int c = bid >> 6, chunk = bid & 63;
    int r0 = chunk * 64;
    if (t < 64) {
      float hvv = Htail[c * kN + r0 + t];
      hv[t] = hvv;
      if (add_deg) {
        float ds = waveSum(hvv);
        if (t == 0 && ds != 0.0f) atomicAdd(&deg[kN + c], ds);
      }
    }
    __syncthreads();
    float s0 = 0.f, s1 = 0.f, s2 = 0.f, s3 = 0.f;
#pragma unroll
    for (int i = 0; i < 64; i += 4) {
      s0 += hv[i]     * X[(size_t)(r0 + i) * kD + t];
      s1 += hv[i + 1] * X[(size_t)(r0 + i + 1) * kD + t];
      s2 += hv[i + 2] * X[(size_t)(r0 + i + 2) * kD + t];
      s3 += hv[i + 3] * X[(size_t)(r0 + i + 3) * kD + t];
    }
    ebpart[(size_t)(c * EB_CHUNKS + chunk) * kD + t] = ((s0 + s1) + (s2 + s3));
  } else if (bid < 1280) {
    int m = (bid - 256) * 4 + wq;
    int cnt = col_cnt[m];
    if (lane < cnt) { sidx[wq][lane] = col_idx[m * COLCAP + lane]; sval[wq][lane] = col_val[m * COLCAP + lane]; }
    __syncthreads();
    float4 a0 = {0,0,0,0}, a1 = {0,0,0,0}, a2 = {0,0,0,0}, a3 = {0,0,0,0};
    int e = 0;
    for (; e + 3 < cnt; e += 4) {
      float v0 = sval[wq][e],     v1 = sval[wq][e + 1];
      float v2 = sval[wq][e + 2], v3 = sval[wq][e + 3];
      float4 x0 = *(const float4*)&X[(size_t)sidx[wq][e] * kD + lane * 4];
      float4 x1 = *(const float4*)&X[(size_t)sidx[wq][e + 1] * kD + lane * 4];
      float4 x2 = *(const float4*)&X[(size_t)sidx[wq][e + 2] * kD + lane * 4];
      float4 x3 = *(const float4*)&X[(size_t)sidx[wq][e + 3] * kD + lane * 4];
      a0.x += v0 * x0.x; a0.y += v0 * x0.y; a0.z += v0 * x0.z; a0.w += v0 * x0.w;
      a1.x += v1 * x1.x; a1.y += v1 * x1.y; a1.z += v1 * x1.z; a1.w += v1 * x1.w;
      a2.x += v2 * x2.x; a2.y += v2 * x2.y; a2.z += v2 * x2.z; a2.w += v2 * x2.w;
      a3.x += v3 * x3.x; a3.y += v3 * x3.y; a3.z += v3 * x3.z; a3.w += v3 * x3.w;
    }
    for (; e < cnt; ++e) {
      float v0 = sval[wq][e];
      float4 x0 = *(const float4*)&X[(size_t)sidx[wq][e] * kD + lane * 4];
      a0.x += v0 * x0.x; a0.y += v0 * x0.y; a0.z += v0 * x0.z; a0.w += v0 * x0.w;
    }
    float ax = (a0.x + a1.x) + (a2.x + a3.x);
    float ay = (a0.y + a1.y) + (a2.y + a3.y);
    float az = (a0.z + a1.z) + (a2.z + a3.z);
    float aw4 = (a0.w + a1.w) + (a2.w + a3.w);
    float inv = 1.0f / deg[m];
    ax *= inv; ay *= inv; az *= inv; aw4 *= inv;
    float mean = waveSum(ax + ay + az + aw4) * (1.0f / kD);
    float dx = ax - mean, dy = ay - mean, dz = az - mean, dw = aw4 - mean;
    float var = waveSum(dx * dx + dy * dy + dz * dz + dw * dw) * (1.0f / kD);
    float rstd = rsqrtf(var + kLnEps);
    float4 gv = *(const float4*)&g[lane * 4];
    float4 bv = *(const float4*)&b[lane * 4];
    float o0 = dx * rstd * gv.x + bv.x, o1 = dy * rstd * gv.y + bv.y;
    float o2 = dz * rstd * gv.z + bv.z, o3 = dw * rstd * gv.w + bv.w;
    int off = fragOff(m, lane * 4);
    short4 hi, lo;
    hi.x = f2bf(o0); lo.x = f2bf(o0 - bf2f(hi.x));
    hi.y = f2bf(o1); lo.y = f2bf(o1 - bf2f(hi.y));
    hi.z = f2bf(o2); lo.z = f2bf(o2 - bf2f(hi.z));
    hi.w = f2bf(o3); lo.w = f2bf(o3 - bf2f(hi.w));
    *(short4*)&Enh[off] = hi;
    *(short4*)&Enl[off] = lo;
  } else {
    int row = (bid - 1280) * 4 + wq;
    float4 v = *(const float4*)&X[(size_t)row * kD + lane * 4];
    float s = waveSum(v.x + v.y + v.z + v.w);
    float mean = s * (1.0f / kD);
    float dx = v.x - mean, dy = v.y - mean, dz = v.z - mean, dw = v.w - mean;
    float q = waveSum(dx * dx + dy * dy + dz * dz + dw * dw);
    float rstd = rsqrtf(q * (1.0f / kD) + kLnEps);
    float4 gv = *(const float4*)&g[lane * 4];
    float4 bv = *(const float4*)&b[lane * 4];
    float o0 = dx * rstd * gv.x + bv.x, o1 = dy * rstd * gv.y + bv.y;
    float o2 = dz * rstd * gv.z + bv.z, o3 = dw * rstd * gv.w + bv.w;
    int off = fragOff(row, lane * 4);
    short4 hi, lo;
    hi.x = f2bf(o0); lo.x = f2bf(o0 - bf2f(hi.x));
    hi.y = f2bf(o1); lo.y = f2bf(o1 - bf2f(hi.y));
    hi.z = f2bf(o2); lo.z = f2bf(o2 - bf2f(hi.z));
    hi.w = f2bf(o3); lo.w = f2bf(o3 - bf2f(hi.w));
    *(short4*)&Xnh[off] = hi;
    *(short4*)&Xnl[off] = lo;
  }
}

struct GArg {
  const short* Ah; const short* Al; const short* Wh; const short* Wl;
  const float* bias; float* C; const float* blend;
  short* Ch; short* Cl; int mode;
};
struct FArg {
  const float* part; const float* deg; const float* g; const float* b;
  const float* Wkt_w; const float* Wkt_b; const float* Wks_w; const float* Wks_b;
  float* K;
};

__global__ __launch_bounds__(256) void k_fgemm(GArg a0, GArg a1, FArg f) {
  int t = threadIdx.x;
  if (blockIdx.z == 2) {
    if (blockIdx.x != 0 || blockIdx.y != 0) return;
    __shared__ float er[4][kD];
    __shared__ float sh[4];
    for (int c = 0; c < 4; ++c) {
      float s0 = 0.f, s1 = 0.f, s2 = 0.f, s3 = 0.f;
      float s4 = 0.f, s5 = 0.f, s6 = 0.f, s7 = 0.f;
      const float* pp = f.part + (size_t)c * EB_CHUNKS * kD + t;
#pragma unroll
      for (int k = 0; k < EB_CHUNKS; k += 8) {
        s0 += pp[(k + 0) * kD]; s1 += pp[(k + 1) * kD];
        s2 += pp[(k + 2) * kD]; s3 += pp[(k + 3) * kD];
        s4 += pp[(k + 4) * kD]; s5 += pp[(k + 5) * kD];
        s6 += pp[(k + 6) * kD]; s7 += pp[(k + 7) * kD];
      }
      float s = (((s0 + s1) + (s2 + s3)) + ((s4 + s5) + (s6 + s7))) * (1.0f / f.deg[kN + c]);
      float mean = blockSum256(s, sh) * (1.0f / kD);
      float dv = s - mean;
      float var = blockSum256(dv * dv, sh) * (1.0f / kD);
      er[c][t] = dv * rsqrtf(var + kLnEps) * f.g[t] + f.b[t];
    }
    __syncthreads();
    float a0_ = 0.f, a1_ = 0.f, a2_ = 0.f, a3_ = 0.f;
    for (int k = 0; k < kD; k += 4) {
      float4 wt = *(const float4*)&f.Wkt_w[(size_t)t * kD + k];
      float4 ws = *(const float4*)&f.Wks_w[(size_t)t * kD + k];
      float4 e0 = *(const float4*)&er[0][k];
      float4 e1 = *(const float4*)&er[1][k];
      float4 e2 = *(const float4*)&er[2][k];
      float4 e3 = *(const float4*)&er[3][k];
      a0_ += e0.x * wt.x + e0.y * wt.y + e0.z * wt.z + e0.w * wt.w;
      a1_ += e1.x * wt.x + e1.y * wt.y + e1.z * wt.z + e1.w * wt.w;
      a2_ += e2.x * wt.x + e2.y * wt.y + e2.z * wt.z + e2.w * wt.w;
      a3_ += e3.x * ws.x + e3.y * ws.y + e3.z * ws.z + e3.w * ws.w;
    }
    float bt = f.Wkt_b[t];
    f.K[(size_t)(kN + 0) * kD + t] = a0_ + bt;
    f.K[(size_t)(kN + 1) * kD + t] = a1_ + bt;
    f.K[(size_t)(kN + 2) * kD + t] = a2_ + bt;
    f.K[(size_t)(kN + 3) * kD + t] = a3_ + f.Wks_b[t];
    return;
  }
  GArg ga = blockIdx.z ? a1 : a0;
  int wv = t >> 6, lane = t & 63;
  int l15 = lane & 15, sub = lane >> 4;
  int mt = blockIdx.x * 4 + wv;
  int ct0 = blockIdx.y * 4;
  const short* Ah = ga.Ah + mt * 4096;
  const short* Al = ga.Al + mt * 4096;
  v4f acc[4] = {{0,0,0,0},{0,0,0,0},{0,0,0,0},{0,0,0,0}};
#pragma unroll
  for (int kc = 0; kc < 8; ++kc) {
    v8bf ahi = *(const v8bf*)(Ah + kc * 512 + lane * 8);
    v8bf alo = *(const v8bf*)(Al + kc * 512 + lane * 8);
#pragma unroll
    for (int c = 0; c < 4; ++c) {
      int wo = (ct0 + c) * 4096 + kc * 512 + lane * 8;
      v8bf bhi = *(const v8bf*)(ga.Wh + wo);
      v8bf blo = *(const v8bf*)(ga.Wl + wo);
      acc[c] = __builtin_amdgcn_mfma_f32_16x16x32_bf16(ahi, bhi, acc[c], 0, 0, 0);
      acc[c] = __builtin_amdgcn_mfma_f32_16x16x32_bf16(alo, bhi, acc[c], 0, 0, 0);
      acc[c] = __builtin_amdgcn_mfma_f32_16x16x32_bf16(ahi, blo, acc[c], 0, 0, 0);
    }
  }
  int row0 = mt * 16, col0 = blockIdx.y * 64;
#pragma unroll
  for (int c = 0; c < 4; ++c) {
    int col = col0 + c * 16 + l15;
    float bs = ga.bias[col];
#pragma unroll
    for (int r = 0; r < 4; ++r) {
      int row = row0 + sub * 4 + r;
      float v = acc[c][r] + bs;
      if (ga.mode == 1) {
        float x0 = ga.blend[(size_t)row * kD + col];
        v = 0.5f * fmaxf(v, 0.0f) + 0.5f * x0;
      }
      ga.C[(size_t)row * kD + col] = v;
      if (ga.Ch) {
        int off = fragOff(row, col);
        short h = f2bf(v);
        ga.Ch[off] = h;
        ga.Cl[off] = f2bf(v - bf2f(h));
      }
    }
  }
}

__global__ __launch_bounds__(256) void k_fgemm_ab(
    const short* __restrict__ Ah, const short* __restrict__ Al,
    const short* __restrict__ Wah, const short* __restrict__ Wal,
    const float* __restrict__ ba,
    const short* __restrict__ Wbh, const short* __restrict__ Wbl,
    const float* __restrict__ bbv,
    const float* __restrict__ cw, float* __restrict__ gpart) {
  int t = threadIdx.x;
  int wv = t >> 6, lane = t & 63;
  int l15 = lane & 15, sub = lane >> 4;
  int mt = blockIdx.x * 4 + wv;
  int ct0 = blockIdx.y * 4;
  const short* Ahp = Ah + mt * 4096;
  const short* Alp = Al + mt * 4096;
  v4f acca[4] = {{0,0,0,0},{0,0,0,0},{0,0,0,0},{0,0,0,0}};
  v4f accb[4] = {{0,0,0,0},{0,0,0,0},{0,0,0,0},{0,0,0,0}};
#pragma unroll
  for (int kc = 0; kc < 8; ++kc) {
    v8bf ahi = *(const v8bf*)(Ahp + kc * 512 + lane * 8);
    v8bf alo = *(const v8bf*)(Alp + kc * 512 + lane * 8);
#pragma unroll
    for (int c = 0; c < 4; ++c) {
      int wo = (ct0 + c) * 4096 + kc * 512 + lane * 8;
      v8bf wah = *(const v8bf*)(Wah + wo);
      v8bf wal = *(const v8bf*)(Wal + wo);
      acca[c] = __builtin_amdgcn_mfma_f32_16x16x32_bf16(ahi, wah, acca[c], 0, 0, 0);
      acca[c] = __builtin_amdgcn_mfma_f32_16x16x32_bf16(alo, wah, acca[c], 0, 0, 0);
      acca[c] = __builtin_amdgcn_mfma_f32_16x16x32_bf16(ahi, wal, acca[c], 0, 0, 0);
      v8bf wbh = *(const v8bf*)(Wbh + wo);
      v8bf wbl = *(const v8bf*)(Wbl + wo);
      accb[c] = __builtin_amdgcn_mfma_f32_16x16x32_bf16(ahi, wbh, accb[c], 0, 0, 0);
      accb[c] = __builtin_amdgcn_mfma_f32_16x16x32_bf16(alo, wbh, accb[c], 0, 0, 0);
      accb[c] = __builtin_amdgcn_mfma_f32_16x16x32_bf16(ahi, wbl, accb[c], 0, 0, 0);
    }
  }
  int row0 = mt * 16, col0 = blockIdx.y * 64;
  float rs[4] = {0.f, 0.f, 0.f, 0.f};
#pragma unroll
  for (int c = 0; c < 4; ++c) {
    int col = col0 + c * 16 + l15;
    float bac = ba[col], bbc = bbv[col], cwc = cw[col];
#pragma unroll
    for (int r = 0; r < 4; ++r) {
      float a = tanhf(acca[c][r] + bac);
      float b = 1.0f / (1.0f + __expf(-(accb[c][r] + bbc)));
      rs[r] += a * b * cwc;
    }
  }
#pragma unroll
  for (int r = 0; r < 4; ++r) {
    rs[r] += __shfl_xor(rs[r], 1);
    rs[r] += __shfl_xor(rs[r], 2);
    rs[r] += __shfl_xor(rs[r], 4);
    rs[r] += __shfl_xor(rs[r], 8);
  }
  if (l15 == 0) {
#pragma unroll
    for (int r = 0; r < 4; ++r)
      gpart[(size_t)blockIdx.y * kN + row0 + sub * 4 + r] = rs[r];
  }
}

__global__ __launch_bounds__(256) void k_attn(
    const float* __restrict__ q, const float* __restrict__ kbuf,
    const int* __restrict__ row_cnt, const int* __restrict__ row_idx,
    short* __restrict__ fAh, short* __restrict__ fAl) {
  __shared__ int sm[ROWCAP];
  __shared__ float qls[kD];
  __shared__ float pls[8][ROWCAP];
  int n = blockIdx.x, t = threadIdx.x;
  int cnt = row_cnt[n];
  if (t < cnt) sm[t] = row_idx[n * ROWCAP + t];
  qls[t] = q[(size_t)n * kD + t];
  __syncthreads();
  int h = t >> 5, j = t & 31;
  float4 qv[8];
#pragma unroll
  for (int d4 = 0; d4 < 8; ++d4) qv[d4] = *(const float4*)&qls[h * 32 + d4 * 4];
  float s1 = 0.f, s2 = 0.f;
  if (j < cnt) {
    const float* kr = &kbuf[(size_t)sm[j] * kD + h * 32];
#pragma unroll
    for (int d4 = 0; d4 < 8; ++d4) {
      float4 kv = *(const float4*)&kr[d4 * 4];
      s1 += qv[d4].x * kv.x + qv[d4].y * kv.y + qv[d4].z * kv.z + qv[d4].w * kv.w;
    }
  }
  if (j + 32 < cnt) {
    const float* kr = &kbuf[(size_t)sm[j + 32] * kD + h * 32];
#pragma unroll
    for (int d4 = 0; d4 < 8; ++d4) {
      float4 kv = *(const float4*)&kr[d4 * 4];
      s2 += qv[d4].x * kv.x + qv[d4].y * kv.y + qv[d4].z * kv.z + qv[d4].w * kv.w;
    }
  }
  s1 *= kScale; s2 *= kScale;
  float v1 = (j < cnt) ? s1 : -3.4e38f;
  float v2 = (j + 32 < cnt) ? s2 : -3.4e38f;
  float mx = fmaxf(v1, v2);
#pragma unroll
  for (int mm = 16; mm >= 1; mm >>= 1) mx = fmaxf(mx, __shfl_xor(mx, mm));
  float p1 = (j < cnt) ? __expf(s1 - mx) : 0.0f;
  float p2 = (j + 32 < cnt) ? __expf(s2 - mx) : 0.0f;
  float ssum = p1 + p2;
#pragma unroll
  for (int mm = 16; mm >= 1; mm >>= 1) ssum += __shfl_xor(ssum, mm);
  float inv = 1.0f / ssum;
  pls[h][j] = p1 * inv;
  pls[h][j + 32] = p2 * inv;
  __syncthreads();
  const float* kb = kbuf + t;
  float ac0 = 0.f, ac1 = 0.f, ac2 = 0.f, ac3 = 0.f;
  int e = 0;
  for (; e + 3 < cnt; e += 4) {
    ac0 += pls[h][e]     * kb[(size_t)sm[e] * kD];
    ac1 += pls[h][e + 1] * kb[(size_t)sm[e + 1] * kD];
    ac2 += pls[h][e + 2] * kb[(size_t)sm[e + 2] * kD];
    ac3 += pls[h][e + 3] * kb[(size_t)sm[e + 3] * kD];
  }
  for (; e < cnt; ++e) ac0 += pls[h][e] * kb[(size_t)sm[e] * kD];
  float v = (ac0 + ac1) + (ac2 + ac3);
  int off = fragOff(n, t);
  short hh = f2bf(v);
  fAh[off] = hh;
  fAl[off] = f2bf(v - bf2f(hh));
}

__global__ __launch_bounds__(256) void k_pool_part(
    const float* __restrict__ gpart, const float* __restrict__ cb,
    const float* __restrict__ feat, float* __restrict__ part) {
  __shared__ float sh[4];
  int b = blockIdx.x, t = threadIdx.x;
  float cb0 = cb[0];
  float mx = -3.4e38f;
  for (int i = t; i < kN; i += 256) {
    float a = gpart[i] + gpart[kN + i] + gpart[2 * kN + i] + gpart[3 * kN + i] + cb0;
    mx = fmaxf(mx, a);
  }
  mx = waveMax(mx);
  int lane = t & 63, w = t >> 6;
  __syncthreads();
  if (lane == 0) sh[w] = mx;
  __syncthreads();
  mx = fmaxf(fmaxf(sh[0], sh[1]), fmaxf(sh[2], sh[3]));
  __syncthreads();
  float s = 0.0f;
  for (int i = t; i < kN; i += 256) {
    float a = gpart[i] + gpart[kN + i] + gpart[2 * kN + i] + gpart[3 * kN + i] + cb0;
    s += expf(a - mx);
  }
  s = blockSum256(s, sh);
  float inv = 1.0f / s;
  float acc = 0.0f;
  for (int r = 0; r < 64; ++r) {
    int n = b * 64 + r;
    float a = gpart[n] + gpart[kN + n] + gpart[2 * kN + n] + gpart[3 * kN + n] + cb0;
    float p = expf(a - mx) * inv;
    acc += p * feat[(size_t)n * kD + t];
  }
  part[(size_t)b * kD + t] = acc;
}

__global__ __launch_bounds__(256) void k_pool_fin(
    const float* __restrict__ part, const float* __restrict__ out_w,
    const float* __restrict__ out_b, float* __restrict__ out) {
  __shared__ float pooled[kD];
  int d = threadIdx.x;
  float s = 0.0f;
#pragma unroll
  for (int b = 0; b < 64; ++b) s += part[(size_t)b * kD + d];
  pooled[d] = s;
  __syncthreads();
  if (d < 4) {
    float o = out_b[d];
    for (int i = 0; i < kD; ++i) o += pooled[i] * out_w[(size_t)d * kD + i];
    out[d] = o;
  }
}

// ======================= cooperative mega kernel =======================
struct MegaP {
  const float* X; const float* H;
  const float* Wq_b; const float* Wkn_b;
  const float* Wkt_w; const float* Wkt_b; const float* Wks_w; const float* Wks_b;
  const float* fc_b; const float* ln_g; const float* ln_b;
  const float* ga_b; const float* gb_b; const float* cw; const float* cb;
  const float* out_w; const float* out_b;
  const float* wsrc[8];
  int* row_cnt; int* row_idx; int* col_cnt; int* col_idx; float* col_val;
  float* Htail; float* deg;
  float* qbuf; float* kbuf; float* buf0; float* buf1;
  float* ebpart; float* gpart; float* ppart;
  short* whi; short* wlo; short* Xnh; short* Xnl; short* Enh; short* Enl;
  short* fAh; short* fAl; short* b1h; short* b1l;
  float* out;
};

__device__ __forceinline__ void gemm_unit(
    const short* __restrict__ Ah, const short* __restrict__ Al,
    const short* __restrict__ Wh, const short* __restrict__ Wl,
    const float* __restrict__ bias, float* __restrict__ C,
    const float* __restrict__ blend, short* Ch, short* Cl, int mode, int ub) {
  int t = threadIdx.x;
  int wv = t >> 6, lane = t & 63;
  int l15 = lane & 15, sub = lane >> 4;
  int x = ub & 63, y = ub >> 6;
  int mt = x * 4 + wv, ct0 = y * 4;
  const short* Ap = Ah + mt * 4096;
  const short* Alp = Al + mt * 4096;
  v4f acc[4] = {{0,0,0,0},{0,0,0,0},{0,0,0,0},{0,0,0,0}};
#pragma unroll
  for (int kc = 0; kc < 8; ++kc) {
    v8bf ahi = *(const v8bf*)(Ap + kc * 512 + lane * 8);
    v8bf alo = *(const v8bf*)(Alp + kc * 512 + lane * 8);
#pragma unroll
    for (int c = 0; c < 4; ++c) {
      int wo = (ct0 + c) * 4096 + kc * 512 + lane * 8;
      v8bf bhi = *(const v8bf*)(Wh + wo);
      v8bf blo = *(const v8bf*)(Wl + wo);
      acc[c] = __builtin_amdgcn_mfma_f32_16x16x32_bf16(ahi, bhi, acc[c], 0, 0, 0);
      acc[c] = __builtin_amdgcn_mfma_f32_16x16x32_bf16(alo, bhi, acc[c], 0, 0, 0);
      acc[c] = __builtin_amdgcn_mfma_f32_16x16x32_bf16(ahi, blo, acc[c], 0, 0, 0);
    }
  }
  int row0 = mt * 16, col0 = y * 64;
#pragma unroll
  for (int c = 0; c < 4; ++c) {
    int col = col0 + c * 16 + l15;
    float bs = bias[col];
#pragma unroll
    for (int r = 0; r < 4; ++r) {
      int row = row0 + sub * 4 + r;
      float v = acc[c][r] + bs;
      if (mode == 1) {
        float x0 = blend[(size_t)row * kD + col];
        v = 0.5f * fmaxf(v, 0.0f) + 0.5f * x0;
      }
      C[(size_t)row * kD + col] = v;
      if (Ch) {
        int off = fragOff(row, col);
        short h = f2bf(v);
        Ch[off] = h;
        Cl[off] = f2bf(v - bf2f(h));
      }
    }
  }
}

__global__ __launch_bounds__(256, 4) void k_mega(MegaP P) {
  cg::grid_group grid = cg::this_grid();
  __shared__ __align__(16) char sm_raw[4608];
  const int gsz = gridDim.x;
  int b = blockIdx.x, t = threadIdx.x;
  int wq = t >> 6, lane = t & 63;

  // ---- P0: zero col_cnt + weight presplit ----
  for (int i = b * 256 + t; i < kN; i += gsz * 256) P.col_cnt[i] = 0;
  for (int i = b * 256 + t; i < 8 * 65536; i += gsz * 256) {
    int mat = i >> 16, e = i & 65535;
    int out = e >> 8, kk = e & 255;
    float v = P.wsrc[mat][e];
    short h = f2bf(v);
    int base = mat * 65536 + fragOff(out, kk);
    P.whi[base] = h;
    P.wlo[base] = f2bf(v - bf2f(h));
  }
  grid.sync();

  // ---- P1: build CSR/CSC + Htail (1 wave per row) ----
  for (int n4 = b; n4 < kN / 4; n4 += gsz) {
    int n = n4 * 4 + wq;
    const float* hrow = P.H + (size_t)n * kM;
    unsigned long long below = (1ull << lane) - 1ull;
    int cnt = 0;
    float tv = (lane < 4) ? hrow[4096 + lane] : 0.0f;
    if (lane < 4) P.Htail[lane * kN + n] = tv;
#pragma unroll
    for (int half = 0; half < 2; ++half) {
      float4 v[8];
#pragma unroll
      for (int c = 0; c < 8; ++c)
        v[c] = *(const float4*)&hrow[(half * 8 + c) * 256 + lane * 4];
#pragma unroll
      for (int c = 0; c < 8; ++c) {
        int mbase = (half * 8 + c) * 256 + lane * 4;
        float vv[4] = {v[c].x, v[c].y, v[c].z, v[c].w};
        unsigned long long bal[4];
#pragma unroll
        for (int j = 0; j < 4; ++j) bal[j] = __ballot(vv[j] != 0.0f);
        int pre = 0, tot = 0;
#pragma unroll
        for (int j = 0; j < 4; ++j) { pre += __popcll(bal[j] & below); tot += __popcll(bal[j]); }
        int local = 0;
#pragma unroll
        for (int j = 0; j < 4; ++j) {
          if (vv[j] != 0.0f) {
            int m = mbase + j;
            int pos = cnt + pre + local;
            if (pos < ROWCAP) P.row_idx[n * ROWCAP + pos] = m;
            int pc = atomicAdd(&P.col_cnt[m], 1);
            if (pc < COLCAP) { P.col_idx[m * COLCAP + pc] = n; P.col_val[m * COLCAP + pc] = vv[j]; }
            local++;
          }
        }
        cnt += tot;
      }
    }
    unsigned long long bal = __ballot(tv != 0.0f);
    if (tv != 0.0f) {
      int pos = cnt + __popcll(bal & below);
      if (pos < ROWCAP) P.row_idx[n * ROWCAP + pos] = 4096 + lane;
    }
    cnt += __popcll(bal);
    if (lane == 0) P.row_cnt[n] = cnt < ROWCAP ? cnt : ROWCAP;
  }
  grid.sync();

  // ---- P2: sort CSC (1 wave per column) ----
  for (int c4 = b; c4 < kN / 4; c4 += gsz) {
    int c = c4 * 4 + wq;
    if (c < 4 && lane == 0) P.deg[kN + c] = 0.0f;
    int cnt = P.col_cnt[c]; if (cnt > COLCAP) cnt = COLCAP;
    int iv = 0x7fffffff; float vv = 0.0f;
    if (lane < cnt) { iv = P.col_idx[c * COLCAP + lane]; vv = P.col_val[c * COLCAP + lane]; }
    float dsum = waveSum(vv);
    int rank = 0;
    for (int j = 0; j < 64; ++j) {
      int ivj = __shfl(iv, j);
      if (ivj < iv) rank++;
    }
    if (lane < cnt) { P.col_idx[c * COLCAP + rank] = iv; P.col_val[c * COLCAP + rank] = vv; }
    if (lane == 0) { P.deg[c] = dsum; P.col_cnt[c] = cnt; }
  }
  grid.sync();

  for (int layer = 0; layer < 2; ++layer) {
    const float* Xc = layer ? P.buf0 : P.X;
    float* Xout = layer ? P.buf1 : P.buf0;
    const float* g = P.ln_g + layer * kD;
    const float* lb = P.ln_b + layer * kD;

    // ---- P3: pre ----
    for (int u = b; u < 2304; u += gsz) {
      __syncthreads();
      if (u < 256) {
        float* hv = (float*)sm_raw;
        int c = u >> 6, chunk = u & 63;
        int r0 = chunk * 64;
        if (t < 64) {
          float hvv = P.Htail[c * kN + r0 + t];
          hv[t] = hvv;
          if (layer == 0) {
            float ds = waveSum(hvv);
            if (t == 0 && ds != 0.0f) atomicAdd(&P.deg[kN + c], ds);
          }
        }
        __syncthreads();
        float s0 = 0.f, s1 = 0.f, s2 = 0.f, s3 = 0.f;
#pragma unroll
        for (int i = 0; i < 64; i += 4) {
          s0 += hv[i]     * Xc[(size_t)(r0 + i) * kD + t];
          s1 += hv[i + 1] * Xc[(size_t)(r0 + i + 1) * kD + t];
          s2 += hv[i + 2] * Xc[(size_t)(r0 + i + 2) * kD + t];
          s3 += hv[i + 3] * Xc[(size_t)(r0 + i + 3) * kD + t];
        }
        P.ebpart[(size_t)(c * EB_CHUNKS + chunk) * kD + t] = ((s0 + s1) + (s2 + s3));
      } else if (u < 1280) {
        int* sidx = (int*)sm_raw;
        float* sval = (float*)(sm_raw + 1024);
        int m = (u - 256) * 4 + wq;
        int cnt = P.col_cnt[m];
        if (lane < cnt) {
          sidx[wq * COLCAP + lane] = P.col_idx[m * COLCAP + lane];
          sval[wq * COLCAP + lane] = P.col_val[m * COLCAP + lane];
        }
        __syncthreads();
        float4 a0 = {0,0,0,0}, a1 = {0,0,0,0}, a2 = {0,0,0,0}, a3 = {0,0,0,0};
        int e = 0;
        for (; e + 3 < cnt; e += 4) {
          float v0 = sval[wq * COLCAP + e],     v1 = sval[wq * COLCAP + e + 1];
          float v2 = sval[wq * COLCAP + e + 2], v3 = sval[wq * COLCAP + e + 3];
          float4 x0 = *(const float4*)&Xc[(size_t)sidx[wq * COLCAP + e] * kD + lane * 4];
          float4 x1 = *(const float4*)&Xc[(size_t)sidx[wq * COLCAP + e + 1] * kD + lane * 4];
          float4 x2 = *(const float4*)&Xc[(size_t)sidx[wq * COLCAP + e + 2] * kD + lane * 4];
          float4 x3 = *(const float4*)&Xc[(size_t)sidx[wq * COLCAP + e + 3] * kD + lane * 4];
          a0.x += v0 * x0.x; a0.y += v0 * x0.y; a0.z += v0 * x0.z; a0.w += v0 * x0.w;
          a1.x += v1 * x1.x; a1.y += v1 * x1.y; a1.z += v1 * x1.z; a1.w += v1 * x1.w;
          a2.x += v2 * x2.x; a2.y += v2 * x2.y; a2.z += v2 * x2.z; a2.w += v2 * x2.w;
          a3.x += v3 * x3.x; a3.y += v3 * x3.y; a3.z += v3 * x3.z; a3.w += v3 * x3.w;
        }
        for (; e < cnt; ++e) {
          float v0 = sval[wq * COLCAP + e];
          float4 x0 = *(const float4*)&Xc[(size_t)sidx[wq * COLCAP + e] * kD + lane * 4];
          a0.x += v0 * x0.x; a0.y += v0 * x0.y; a0.z += v0 * x0.z; a0.w += v0 * x0.w;
        }
        float ax = (a0.x + a1.x) + (a2.x + a3.x);
        float ay = (a0.y + a1.y) + (a2.y + a3.y);
        float az = (a0.z + a1.z) + (a2.z + a3.z);
        float aw4 = (a0.w + a1.w) + (a2.w + a3.w);
        float inv = 1.0f / P.deg[m];
        ax *= inv; ay *= inv; az *= inv; aw4 *= inv;
        float mean = waveSum(ax + ay + az + aw4) * (1.0f / kD);
        float dx = ax - mean, dy = ay - mean, dz = az - mean, dw = aw4 - mean;
        float var = waveSum(dx * dx + dy * dy + dz * dz + dw * dw) * (1.0f / kD);
        float rstd = rsqrtf(var + kLnEps);
        float4 gv = *(const float4*)&g[lane * 4];
        float4 bv = *(const float4*)&lb[lane * 4];
        float o0 = dx * rstd * gv.x + bv.x, o1 = dy * rstd * gv.y + bv.y;
        float o2 = dz * rstd * gv.z + bv.z, o3 = dw * rstd * gv.w + bv.w;
        int off = fragOff(m, lane * 4);
        short4 hi, lo;
        hi.x = f2bf(o0); lo.x = f2bf(o0 - bf2f(hi.x));
        hi.y = f2bf(o1); lo.y = f2bf(o1 - bf2f(hi.y));
        hi.z = f2bf(o2); lo.z = f2bf(o2 - bf2f(hi.z));
        hi.w = f2bf(o3); lo.w = f2bf(o3 - bf2f(hi.w));
        *(short4*)&P.Enh[off] = hi;
        *(short4*)&P.Enl[off] = lo;
      } else {
        int row = (u - 1280) * 4 + wq;
        float4 v = *(const float4*)&Xc[(size_t)row * kD + lane * 4];
        float s = waveSum(v.x + v.y + v.z + v.w);
        float mean = s * (1.0f / kD);
        float dx = v.x - mean, dy = v.y - mean, dz = v.z - mean, dw = v.w - mean;
        float q = waveSum(dx * dx + dy * dy + dz * dz + dw * dw);
        float rstd = rsqrtf(q * (1.0f / kD) + kLnEps);
        float4 gv = *(const float4*)&g[lane * 4];
        float4 bv = *(const float4*)&lb[lane * 4];
        float o0 = dx * rstd * gv.x + bv.x, o1 = dy * rstd * gv.y + bv.y;
        float o2 = dz * rstd * gv.z + bv.z, o3 = dw * rstd * gv.w + bv.w;
        int off = fragOff(row, lane * 4);
        short4 hi, lo;
        hi.x = f2bf(o0); lo.x = f2bf(o0 - bf2f(hi.x));
        hi.y = f2bf(o1); lo.y = f2bf(o1 - bf2f(hi.y));
        hi.z = f2bf(o2); lo.z = f2bf(o2 - bf2f(hi.z));
        hi.w = f2bf(o3); lo.w = f2bf(o3 - bf2f(hi.w));
        *(short4*)&P.Xnh[off] = hi;
        *(short4*)&P.Xnl[off] = lo;
      }
    }
    grid.sync();

    // ---- P4: q-GEMM (256) + kn-GEMM (256) + finktail (1) ----
    for (int u = b; u < 513; u += gsz) {
      if (u < 256) {
        gemm_unit(P.Xnh, P.Xnl, P.whi + (size_t)(0 + layer) * 65536,
                  P.wlo + (size_t)(0 + layer) * 65536, P.Wq_b + layer * kD,
                  P.qbuf, nullptr, nullptr, nullptr, 0, u);
      } else if (u < 512) {
        gemm_unit(P.Enh, P.Enl, P.whi + (size_t)(2 + layer) * 65536,
                  P.wlo + (size_t)(2 + layer) * 65536, P.Wkn_b + layer * kD,
                  P.kbuf, nullptr, nullptr, nullptr, 0, u - 256);
      } else {
        __syncthreads();
        float* er = (float*)sm_raw;
        float* sh = (float*)(sm_raw + 4096);
        const float* Wkt = P.Wkt_w + (size_t)layer * kD * kD;
        const float* Wks = P.Wks_w + (size_t)layer * kD * kD;
        for (int c = 0; c < 4; ++c) {
          float s0 = 0.f, s1 = 0.f, s2 = 0.f, s3 = 0.f;
          float s4 = 0.f, s5 = 0.f, s6 = 0.f, s7 = 0.f;
          const float* pp = P.ebpart + (size_t)c * EB_CHUNKS * kD + t;
#pragma unroll
          for (int k = 0; k < EB_CHUNKS; k += 8) {
            s0 += pp[(k + 0) * kD]; s1 += pp[(k + 1) * kD];
            s2 += pp[(k + 2) * kD]; s3 += pp[(k + 3) * kD];
            s4 += pp[(k + 4) * kD]; s5 += pp[(k + 5) * kD];
            s6 += pp[(k + 6) * kD]; s7 += pp[(k + 7) * kD];
          }
          float s = (((s0 + s1) + (s2 + s3)) + ((s4 + s5) + (s6 + s7))) * (1.0f / P.deg[kN + c]);
          float mean = blockSum256(s, sh) * (1.0f / kD);
          float dv = s - mean;
          float var = blockSum256(dv * dv, sh) * (1.0f / kD);
          er[c * kD + t] = dv * rsqrtf(var + kLnEps) * g[t] + lb[t];
        }
        __syncthreads();
        float a0_ = 0.f, a1_ = 0.f, a2_ = 0.f, a3_ = 0.f;
        for (int k = 0; k < kD; k += 4) {
          float4 wt = *(const float4*)&Wkt[(size_t)t * kD + k];
          float4 ws = *(const float4*)&Wks[(size_t)t * kD + k];
          float4 e0 = *(const float4*)&er[0 * kD + k];
          float4 e1 = *(const float4*)&er[1 * kD + k];
          float4 e2 = *(const float4*)&er[2 * kD + k];
          float4 e3 = *(const float4*)&er[3 * kD + k];
          a0_ += e0.x * wt.x + e0.y * wt.y + e0.z * wt.z + e0.w * wt.w;
          a1_ += e1.x * wt.x + e1.y * wt.y + e1.z * wt.z + e1.w * wt.w;
          a2_ += e2.x * wt.x + e2.y * wt.y + e2.z * wt.z + e2.w * wt.w;
          a3_ += e3.x * ws.x + e3.y * ws.y + e3.z * ws.z + e3.w * ws.w;
        }
        float bt = P.Wkt_b[layer * kD + t];
        P.kbuf[(size_t)(kN + 0) * kD + t] = a0_ + bt;
        P.kbuf[(size_t)(kN + 1) * kD + t] = a1_ + bt;
        P.kbuf[(size_t)(kN + 2) * kD + t] = a2_ + bt;
        P.kbuf[(size_t)(kN + 3) * kD + t] = a3_ + P.Wks_b[layer * kD + t];
      }
    }
    grid.sync();

    // ---- P5: sparse attention ----
    for (int n = b; n < kN; n += gsz) {
      __syncthreads();
      int* sm = (int*)sm_raw;
      float* qls = (float*)(sm_raw + 256);
      float* pls = (float*)(sm_raw + 1280);
      int cnt = P.row_cnt[n];
      if (t < cnt) sm[t] = P.row_idx[n * ROWCAP + t];
      qls[t] = P.qbuf[(size_t)n * kD + t];
      __syncthreads();
      int h = t >> 5, j = t & 31;
      float4 qv[8];
#pragma unroll
      for (int d4 = 0; d4 < 8; ++d4) qv[d4] = *(const float4*)&qls[h * 32 + d4 * 4];
      float s1 = 0.f, s2 = 0.f;
      if (j < cnt) {
        const float* kr = &P.kbuf[(size_t)sm[j] * kD + h * 32];
#pragma unroll
        for (int d4 = 0; d4 < 8; ++d4) {
          float4 kv = *(const float4*)&kr[d4 * 4];
          s1 += qv[d4].x * kv.x + qv[d4].y * kv.y + qv[d4].z * kv.z + qv[d4].w * kv.w;
        }
      }
      if (j + 32 < cnt) {
        const float* kr = &P.kbuf[(size_t)sm[j + 32] * kD + h * 32];
#pragma unroll
        for (int d4 = 0; d4 < 8; ++d4) {
          float4 kv = *(const float4*)&kr[d4 * 4];
          s2 += qv[d4].x * kv.x + qv[d4].y * kv.y + qv[d4].z * kv.z + qv[d4].w * kv.w;
        }
      }
      s1 *= kScale; s2 *= kScale;
      float v1 = (j < cnt) ? s1 : -3.4e38f;
      float v2 = (j + 32 < cnt) ? s2 : -3.4e38f;
      float mx = fmaxf(v1, v2);
#pragma unroll
      for (int mm = 16; mm >= 1; mm >>= 1) mx = fmaxf(mx, __shfl_xor(mx, mm));
      float p1 = (j < cnt) ? __expf(s1 - mx) : 0.0f;
      float p2 = (j + 32 < cnt) ? __expf(s2 - mx) : 0.0f;
      float ssum = p1 + p2;
#pragma unroll
      for (int mm = 16; mm >= 1; mm >>= 1) ssum += __shfl_xor(ssum, mm);
      float inv = 1.0f / ssum;
      pls[h * ROWCAP + j] = p1 * inv;
      pls[h * ROWCAP + j + 32] = p2 * inv;
      __syncthreads();
      const float* kb = P.kbuf + t;
      float ac0 = 0.f, ac1 = 0.f, ac2 = 0.f, ac3 = 0.f;
      int e = 0;
      for (; e + 3 < cnt; e += 4) {
        ac0 += pls[h * ROWCAP + e]     * kb[(size_t)sm[e] * kD];
        ac1 += pls[h * ROWCAP + e + 1] * kb[(size_t)sm[e + 1] * kD];
        ac2 += pls[h * ROWCAP + e + 2] * kb[(size_t)sm[e + 2] * kD];
        ac3 += pls[h * ROWCAP + e + 3] * kb[(size_t)sm[e + 3] * kD];
      }
      for (; e < cnt; ++e) ac0 += pls[h * ROWCAP + e] * kb[(size_t)sm[e] * kD];
      float v = (ac0 + ac1) + (ac2 + ac3);
      int off = fragOff(n, t);
      short hh = f2bf(v);
      P.fAh[off] = hh;
      P.fAl[off] = f2bf(v - bf2f(hh));
    }
    grid.sync();

    // ---- P6: fc GEMM ----
    for (int u = b; u < 256; u += gsz) {
      gemm_unit(P.fAh, P.fAl, P.whi + (size_t)(4 + layer) * 65536,
                P.wlo + (size_t)(4 + layer) * 65536, P.fc_b + layer * kD,
                Xout, Xc, layer ? P.b1h : nullptr, layer ? P.b1l : nullptr, 1, u);
    }
    grid.sync();
  }

  // ---- P7: a/b gated GEMM -> gpart ----
  for (int u = b; u < 256; u += gsz) {
    int wv = t >> 6, lane2 = t & 63;
    int l15 = lane2 & 15, sub = lane2 >> 4;
    int x = u & 63, y = u >> 6;
    int mt = x * 4 + wv, ct0 = y * 4;
    const short* Ahp = P.b1h + mt * 4096;
    const short* Alp = P.b1l + mt * 4096;
    const short* Wah = P.whi + (size_t)6 * 65536;
    const short* Wal = P.wlo + (size_t)6 * 65536;
    const short* Wbh = P.whi + (size_t)7 * 65536;
    const short* Wbl = P.wlo + (size_t)7 * 65536;
    v4f acca[4] = {{0,0,0,0},{0,0,0,0},{0,0,0,0},{0,0,0,0}};
    v4f accb[4] = {{0,0,0,0},{0,0,0,0},{0,0,0,0},{0,0,0,0}};
#pragma unroll
    for (int kc = 0; kc < 8; ++kc) {
      v8bf ahi = *(const v8bf*)(Ahp + kc * 512 + lane2 * 8);
      v8bf alo = *(const v8bf*)(Alp + kc * 512 + lane2 * 8);
#pragma unroll
      for (int c = 0; c < 4; ++c) {
        int wo = (ct0 + c) * 4096 + kc * 512 + lane2 * 8;
        v8bf wah = *(const v8bf*)(Wah + wo);
        v8bf wal = *(const v8bf*)(Wal + wo);
        acca[c] = __builtin_amdgcn_mfma_f32_16x16x32_bf16(ahi, wah, acca[c], 0, 0, 0);
        acca[c] = __builtin_amdgcn_mfma_f32_16x16x32_bf16(alo, wah, acca[c], 0, 0, 0);
        acca[c] = __builtin_amdgcn_mfma_f32_16x16x32_bf16(ahi, wal, acca[c], 0, 0, 0);
        v8bf wbh = *(const v8bf*)(Wbh + wo);
        v8bf wbl = *(const v8bf*)(Wbl + wo);
        accb[c] = __builtin_amdgcn_mfma_f32_16x16x32_bf16(ahi, wbh, accb[c], 0, 0, 0);
        accb[c] = __builtin_amdgcn_mfma_f32_16x16x32_bf16(alo, wbh, accb[c], 0, 0, 0);
        accb[c] = __builtin_amdgcn_mfma_f32_16x16x32_bf16(ahi, wbl, accb[c], 0, 0, 0);
      }
    }
    int row0 = mt * 16, col0 = y * 64;
    float rs[4] = {0.f, 0.f, 0.f, 0.f};
#pragma unroll
    for (int c = 0; c < 4; ++c) {
      int col = col0 + c * 16 + l15;
      float bac = P.ga_b[col], bbc = P.gb_b[col], cwc = P.cw[col];
#pragma unroll
      for (int r = 0; r < 4; ++r) {
        float a = tanhf(acca[c][r] + bac);
        float bsg = 1.0f / (1.0f + __expf(-(accb[c][r] + bbc)));
        rs[r] += a * bsg * cwc;
      }
    }
#pragma unroll
    for (int r = 0; r < 4; ++r) {
      rs[r] += __shfl_xor(rs[r], 1);
      rs[r] += __shfl_xor(rs[r], 2);
      rs[r] += __shfl_xor(rs[r], 4);
      rs[r] += __shfl_xor(rs[r], 8);
    }
    if (l15 == 0) {
#pragma unroll
      for (int r = 0; r < 4; ++r)
        P.gpart[(size_t)y * kN + row0 + sub * 4 + r] = rs[r];
    }
  }
  grid.sync();

  // ---- P8: pool partials ----
  for (int u = b; u < 64; u += gsz) {
    __syncthreads();
    float* sh = (float*)sm_raw;
    float cb0 = P.cb[0];
    float mx = -3.4e38f;
    for (int i = t; i < kN; i += 256) {
      float a = P.gpart[i] + P.gpart[kN + i] + P.gpart[2 * kN + i] + P.gpart[3 * kN + i] + cb0;
      mx = fmaxf(mx, a);
    }
    mx = waveMax(mx);
    int w = t >> 6;
    __syncthreads();
    if (lane == 0) sh[w] = mx;
    __syncthreads();
    mx = fmaxf(fmaxf(sh[0], sh[1]), fmaxf(sh[2], sh[3]));
    __syncthreads();
    float s = 0.0f;
    for (int i = t; i < kN; i += 256) {
      float a = P.gpart[i] + P.gpart[kN + i] + P.gpart[2 * kN + i] + P.gpart[3 * kN + i] + cb0;
      s += expf(a - mx);
    }
    s = blockSum256(s, sh);
    float inv = 1.0f / s;
    float acc = 0.0f;
    for (int r = 0; r < 64; ++r) {
      int n = u * 64 + r;
      float a = P.gpart[n] + P.gpart[kN + n] + P.gpart[2 * kN + n] + P.gpart[3 * kN + n] + cb0;
      float p = expf(a - mx) * inv;
      acc += p * P.buf1[(size_t)n * kD + t];
    }
    P.ppart[(size_t)u * kD + t] = acc;
  }
  grid.sync();

  // ---- P9: pool finish + output ----
  if (b == 0) {
    float* pooled = (float*)sm_raw;
    float s = 0.0f;
#pragma unroll
    for (int q = 0; q < 64; ++q) s += P.ppart[(size_t)q * kD + t];
    pooled[t] = s;
    __syncthreads();
    if (t < 4) {
      float o = P.out_b[t];
      for (int i = 0; i < kD; ++i) o += pooled[i] * P.out_w[(size_t)t * kD + i];
      P.out[t] = o;
    }
  }
}

extern "C" void kernel_launch(void* const* d_in, const int* in_sizes, int n_in,
                              void* d_out, int out_size, void* d_ws, size_t ws_size,
                              hipStream_t stream) {
  (void)in_sizes; (void)n_in; (void)out_size; (void)ws_size;
  const float* X     = (const float*)d_in[0];
  const float* H     = (const float*)d_in[1];
  const float* Wq_w  = (const float*)d_in[2];
  const float* Wq_b  = (const float*)d_in[3];
  const float* Wkn_w = (const float*)d_in[4];
  const float* Wkn_b = (const float*)d_in[5];
  const float* Wkt_w = (const float*)d_in[6];
  const float* Wkt_b = (const float*)d_in[7];
  const float* Wks_w = (const float*)d_in[8];
  const float* Wks_b = (const float*)d_in[9];
  const float* fc_w  = (const float*)d_in[10];
  const float* fc_b  = (const float*)d_in[11];
  const float* ln_g  = (const float*)d_in[12];
  const float* ln_b  = (const float*)d_in[13];
  const float* aw    = (const float*)d_in[14];
  const float* ab    = (const float*)d_in[15];
  const float* bw    = (const float*)d_in[16];
  const float* bb    = (const float*)d_in[17];
  const float* cw    = (const float*)d_in[18];
  const float* cb    = (const float*)d_in[19];
  const float* out_w = (const float*)d_in[20];
  const float* out_b = (const float*)d_in[21];

  char* p = (char*)d_ws;
  auto alloc = [&](size_t bytes) -> void* {
    void* r = (void*)p;
    p += (bytes + 255) & ~(size_t)255;
    return r;
  };
  MegaP P;
  P.row_cnt = (int*)alloc(kN * 4);
  P.row_idx = (int*)alloc((size_t)kN * ROWCAP * 4);
  P.col_cnt = (int*)alloc(kN * 4);
  P.col_idx = (int*)alloc((size_t)kN * COLCAP * 4);
  P.col_val = (float*)alloc((size_t)kN * COLCAP * 4);
  P.Htail   = (float*)alloc((size_t)4 * kN * 4);
  P.deg     = (float*)alloc(kM * 4);
  P.qbuf    = (float*)alloc((size_t)kN * kD * 4);
  P.kbuf    = (float*)alloc((size_t)kM * kD * 4);
  P.buf0    = (float*)alloc((size_t)kN * kD * 4);
  P.buf1    = (float*)alloc((size_t)kN * kD * 4);
  P.ebpart  = (float*)alloc((size_t)4 * EB_CHUNKS * kD * 4);
  P.gpart   = (float*)alloc((size_t)4 * kN * 4);
  P.ppart   = (float*)alloc(64 * kD * 4);
  P.whi     = (short*)alloc((size_t)8 * 65536 * 2);
  P.wlo     = (short*)alloc((size_t)8 * 65536 * 2);
  P.Xnh     = (short*)alloc((size_t)kN * kD * 2);
  P.Xnl     = (short*)alloc((size_t)kN * kD * 2);
  P.Enh     = (short*)alloc((size_t)kN * kD * 2);
  P.Enl     = (short*)alloc((size_t)kN * kD * 2);
  P.fAh     = (short*)alloc((size_t)kN * kD * 2);
  P.fAl     = (short*)alloc((size_t)kN * kD * 2);
  P.b1h     = (short*)alloc((size_t)kN * kD * 2);
  P.b1l     = (short*)alloc((size_t)kN * kD * 2);

  P.X = X; P.H = H;
  P.Wq_b = Wq_b; P.Wkn_b = Wkn_b;
  P.Wkt_w = Wkt_w; P.Wkt_b = Wkt_b; P.Wks_w = Wks_w; P.Wks_b = Wks_b;
  P.fc_b = fc_b; P.ln_g = ln_g; P.ln_b = ln_b;
  P.ga_b = ab; P.gb_b = bb; P.cw = cw; P.cb = cb;
  P.out_w = out_w; P.out_b = out_b;
  P.wsrc[0] = Wq_w;  P.wsrc[1] = Wq_w + 65536;
  P.wsrc[2] = Wkn_w; P.wsrc[3] = Wkn_w + 65536;
  P.wsrc[4] = fc_w;  P.wsrc[5] = fc_w + 65536;
  P.wsrc[6] = aw;    P.wsrc[7] = bw;
  P.out = (float*)d_out;

  // ---- decide cooperative feasibility (deterministic per device) ----
  int dev = 0;
  hipGetDevice(&dev);
  int numCU = 0, coopOK = 0, maxBlk = 0;
  hipDeviceGetAttribute(&numCU, hipDeviceAttributeMultiprocessorCount, dev);
  hipDeviceGetAttribute(&coopOK, hipDeviceAttributeCooperativeLaunch, dev);
  hipError_t oe = hipOccupancyMaxActiveBlocksPerMultiprocessor(&maxBlk, k_mega, 256, 0);
  int gridBlocks = (oe == hipSuccess) ? maxBlk * numCU : 0;
  if (gridBlocks > 1024) gridBlocks = 1024;

  bool launched = false;
  if (coopOK && gridBlocks >= 64) {
    void* args[] = {(void*)&P};
    hipError_t e = hipLaunchCooperativeKernel(k_mega, dim3(gridBlocks), dim3(256),
                                              args, 0, stream);
    launched = (e == hipSuccess);
  }
  if (launched) return;

  // ---- fallback: R10 multi-dispatch path (verbatim) ----
  hipMemsetAsync(P.col_cnt, 0, kN * 4, stream);
  k_build_csr<<<kN / 4, 256, 0, stream>>>(H, P.row_cnt, P.row_idx, P.col_cnt,
                                          P.col_idx, P.col_val, P.Htail);
  k_sort_csc<<<kN / 4, 256, 0, stream>>>(P.col_cnt, P.col_idx, P.col_val, P.deg);
  WPtrs wp = {{Wq_w, Wq_w + 65536, Wkn_w, Wkn_w + 65536, fc_w, fc_w + 65536, aw, bw}};
  k_wsplit<<<dim3(256, 8), 256, 0, stream>>>(wp, P.whi, P.wlo);

  FArg fdummy = {};
  GArg gdummy = {};
  for (int layer = 0; layer < 2; ++layer) {
    const float* Xc = layer ? P.buf0 : X;
    float* Xout = layer ? P.buf1 : P.buf0;
    size_t bo = (size_t)layer * kD;
    k_pre<<<2304, 256, 0, stream>>>(Xc, P.Htail, P.col_cnt, P.col_idx, P.col_val,
                                    P.deg, ln_g + bo, ln_b + bo, P.Xnh, P.Xnl,
                                    P.Enh, P.Enl, P.ebpart, layer == 0);
    GArg qa = {P.Xnh, P.Xnl, P.whi + (size_t)(0 + layer) * 65536,
               P.wlo + (size_t)(0 + layer) * 65536, Wq_b + bo, P.qbuf,
               nullptr, nullptr, nullptr, 0};
    GArg ka = {P.Enh, P.Enl, P.whi + (size_t)(2 + layer) * 65536,
               P.wlo + (size_t)(2 + layer) * 65536, Wkn_b + bo, P.kbuf,
               nullptr, nullptr, nullptr, 0};
    FArg fk = {P.ebpart, P.deg, ln_g + bo, ln_b + bo,
               Wkt_w + (size_t)layer * kD * kD, Wkt_b + bo,
               Wks_w + (size_t)layer * kD * kD, Wks_b + bo, P.kbuf};
    k_fgemm<<<dim3(64, 4, 3), 256, 0, stream>>>(qa, ka, fk);
    k_attn<<<kN, 256, 0, stream>>>(P.qbuf, P.kbuf, P.row_cnt, P.row_idx, P.fAh, P.fAl);
    GArg fa = {P.fAh, P.fAl, P.whi + (size_t)(4 + layer) * 65536,
               P.wlo + (size_t)(4 + layer) * 65536, fc_b + bo, Xout, Xc,
               layer ? P.b1h : nullptr, layer ? P.b1l : nullptr, 1};
    k_fgemm<<<dim3(64, 4, 1), 256, 0, stream>>>(fa, gdummy, fdummy);
  }

  k_fgemm_ab<<<dim3(64, 4), 256, 0, stream>>>(
      P.b1h, P.b1l, P.whi + (size_t)6 * 65536, P.wlo + (size_t)6 * 65536, ab,
      P.whi + (size_t)7 * 65536, P.wlo + (size_t)7 * 65536, bb, cw, P.gpart);
  k_pool_part<<<64, 256, 0, stream>>>(P.gpart, cb, P.buf1, P.ppart);
  k_pool_fin<<<1, 256, 0, stream>>>(P.ppart, out_w, out_b, (float*)d_out);
}

// Round 13
// 216.369 us; speedup vs baseline: 5.3949x; 5.3949x over previous
//
#include <hip/hip_runtime.h>
#include <math.h>

constexpr int kN = 4096;
constexpr int kM = 4100;
constexpr int kD = 256;
constexpr int ROWCAP = 64;
constexpr int COLCAP = 64;
constexpr int EB_CHUNKS = 64;   // 64 chunks x 64 rows per big column
constexpr float kLnEps = 1e-5f;
constexpr float kScale = 0.17677669529663687f; // 1/sqrt(32)

typedef short v8bf __attribute__((ext_vector_type(8)));
typedef float v4f  __attribute__((ext_vector_type(4)));

__device__ __forceinline__ float waveSum(float v) {
#pragma unroll
  for (int m = 32; m >= 1; m >>= 1) v += __shfl_xor(v, m);
  return v;
}
__device__ __forceinline__ float waveMax(float v) {
#pragma unroll
  for (int m = 32; m >= 1; m >>= 1) v = fmaxf(v, __shfl_xor(v, m));
  return v;
}
__device__ __forceinline__ float blockSum256(float v, float* sh) {
  v = waveSum(v);
  int lane = threadIdx.x & 63, w = threadIdx.x >> 6;
  __syncthreads();
  if (lane == 0) sh[w] = v;
  __syncthreads();
  return sh[0] + sh[1] + sh[2] + sh[3];
}

__device__ __forceinline__ short f2bf(float x) {
  unsigned u = __float_as_uint(x);
  unsigned r = (u + 0x7fffu + ((u >> 16) & 1u)) >> 16;
  return (short)r;
}
__device__ __forceinline__ float bf2f(short h) {
  return __uint_as_float(((unsigned)(unsigned short)h) << 16);
}
// fragment-order offset for element (row n, col k) of a [*,256] matrix
__device__ __forceinline__ int fragOff(int n, int k) {
  return ((n >> 4) << 12) + ((k >> 5) << 9) + (((k >> 3) & 3) << 7) + ((n & 15) << 3) + (k & 7);
}

// ---------------- weight presplit (runs FIRST; also zeroes col_cnt) ----------
struct WPtrs { const float* w[8]; };
__global__ __launch_bounds__(256) void k_wsplit(
    WPtrs wp, short* __restrict__ hi, short* __restrict__ lo,
    int* __restrict__ col_cnt) {
  int mat = blockIdx.y;
  int i = blockIdx.x * 256 + threadIdx.x;   // i = out*256 + k
  if (mat == 0 && blockIdx.x < 16) col_cnt[blockIdx.x * 256 + threadIdx.x] = 0;
  int out = i >> 8, k = i & 255;
  float v = wp.w[mat][i];
  short h = f2bf(v);
  size_t base = (size_t)mat * 65536 + fragOff(out, k);
  hi[base] = h;
  lo[base] = f2bf(v - bf2f(h));
}

// ---------------- sparse build ----------------
__global__ __launch_bounds__(256) void k_build_csr(
    const float* __restrict__ H, int* __restrict__ row_cnt, int* __restrict__ row_idx,
    int* __restrict__ col_cnt, int* __restrict__ col_idx, float* __restrict__ col_val,
    float* __restrict__ Htail) {
  int n = (blockIdx.x * blockDim.x + threadIdx.x) >> 6;
  int lane = threadIdx.x & 63;
  const float* hrow = H + (size_t)n * kM;
  float4 v[16];
#pragma unroll
  for (int c = 0; c < 16; ++c) v[c] = *(const float4*)&hrow[c * 256 + lane * 4];
  float tv = (lane < 4) ? hrow[4096 + lane] : 0.0f;
  if (lane < 4) Htail[lane * kN + n] = tv;
  unsigned long long below = (1ull << lane) - 1ull;
  int cnt = 0;
#pragma unroll
  for (int c = 0; c < 16; ++c) {
    int mbase = c * 256 + lane * 4;
    float vv[4] = {v[c].x, v[c].y, v[c].z, v[c].w};
    unsigned long long bal[4];
#pragma unroll
    for (int j = 0; j < 4; ++j) bal[j] = __ballot(vv[j] != 0.0f);
    int pre = 0, tot = 0;
#pragma unroll
    for (int j = 0; j < 4; ++j) { pre += __popcll(bal[j] & below); tot += __popcll(bal[j]); }
    int local = 0;
#pragma unroll
    for (int j = 0; j < 4; ++j) {
      if (vv[j] != 0.0f) {
        int m = mbase + j;
        int pos = cnt + pre + local;
        if (pos < ROWCAP) row_idx[n * ROWCAP + pos] = m;
        int pc = atomicAdd(&col_cnt[m], 1);
        if (pc < COLCAP) { col_idx[m * COLCAP + pc] = n; col_val[m * COLCAP + pc] = vv[j]; }
        local++;
      }
    }
    cnt += tot;
  }
  unsigned long long bal = __ballot(tv != 0.0f);
  if (tv != 0.0f) {
    int pos = cnt + __popcll(bal & below);
    if (pos < ROWCAP) row_idx[n * ROWCAP + pos] = 4096 + lane;
  }
  cnt += __popcll(bal);
  if (lane == 0) row_cnt[n] = cnt < ROWCAP ? cnt : ROWCAP;
}

__global__ __launch_bounds__(256) void k_sort_csc(
    int* __restrict__ col_cnt, int* __restrict__ col_idx, float* __restrict__ col_val,
    float* __restrict__ deg) {
  int c = (blockIdx.x * blockDim.x + threadIdx.x) >> 6;
  int lane = threadIdx.x & 63;
  if (c < 4 && lane == 0) deg[kN + c] = 0.0f;
  int cnt = col_cnt[c]; if (cnt > COLCAP) cnt = COLCAP;
  int iv = 0x7fffffff; float vv = 0.0f;
  if (lane < cnt) { iv = col_idx[c * COLCAP + lane]; vv = col_val[c * COLCAP + lane]; }
  float dsum = waveSum(vv);
  int rank = 0;
  for (int j = 0; j < 64; ++j) {
    int ivj = __shfl(iv, j);
    if (ivj < iv) rank++;
  }
  if (lane < cnt) { col_idx[c * COLCAP + rank] = iv; col_val[c * COLCAP + rank] = vv; }
  if (lane == 0) { deg[c] = dsum; col_cnt[c] = cnt; }
}

// ---------------- fused per-layer pre-pass ----------------
// blocks [0,256): big-column 64-row chunk partial sums (launched FIRST: these
//   carry the longest serial chains)
// blocks [256,1280): E rows (CSC gather + LN) -> En frags (hi/lo)
// blocks [1280,2304): LN(X) -> Xn frags (hi/lo)
__global__ __launch_bounds__(256) void k_pre(
    const float* __restrict__ X, const float* __restrict__ Htail,
    const int* __restrict__ col_cnt, const int* __restrict__ col_idx,
    const float* __restrict__ col_val, float* __restrict__ deg,
    const float* __restrict__ g, const float* __restrict__ b,
    short* __restrict__ Xnh, short* __restrict__ Xnl,
    short* __restrict__ Enh, short* __restrict__ Enl,
    float* __restrict__ ebpart, int add_deg) {
  __shared__ int sidx[4][COLCAP];
  __shared__ float sval[4][COLCAP];
  int bid = blockIdx.x, t = threadIdx.x;
  int wq = t >> 6, lane = t & 63;
  if (bid < 256) {
    __shared__ float hv[64];
    int c = bid >> 6, chunk = bid & 63;
    int r0 = chunk * 64;
    if (t < 64) {
      float hvv = Htail[c * kN + r0 + t];
      hv[t] = hvv;
      if (add_deg) {
        float ds = waveSum(hvv);   // values in {0,1}: integer-exact partial
        if (t == 0 && ds != 0.0f) atomicAdd(&deg[kN + c], ds);
      }
    }
    __syncthreads();
    float s0 = 0.f, s1 = 0.f, s2 = 0.f, s3 = 0.f;
#pragma unroll
    for (int i = 0; i < 64; i += 4) {
      s0 += hv[i]     * X[(size_t)(r0 + i) * kD + t];
      s1 += hv[i + 1] * X[(size_t)(r0 + i + 1) * kD + t];
      s2 += hv[i + 2] * X[(size_t)(r0 + i + 2) * kD + t];
      s3 += hv[i + 3] * X[(size_t)(r0 + i + 3) * kD + t];
    }
    ebpart[(size_t)(c * EB_CHUNKS + chunk) * kD + t] = ((s0 + s1) + (s2 + s3));
  } else if (bid < 1280) {
    int m = (bid - 256) * 4 + wq;
    int cnt = col_cnt[m];
    if (lane < cnt) { sidx[wq][lane] = col_idx[m * COLCAP + lane]; sval[wq][lane] = col_val[m * COLCAP + lane]; }
    __syncthreads();
    float4 a0 = {0,0,0,0}, a1 = {0,0,0,0}, a2 = {0,0,0,0}, a3 = {0,0,0,0};
    int e = 0;
    for (; e + 3 < cnt; e += 4) {
      float v0 = sval[wq][e],     v1 = sval[wq][e + 1];
      float v2 = sval[wq][e + 2], v3 = sval[wq][e + 3];
      float4 x0 = *(const float4*)&X[(size_t)sidx[wq][e] * kD + lane * 4];
      float4 x1 = *(const float4*)&X[(size_t)sidx[wq][e + 1] * kD + lane * 4];
      float4 x2 = *(const float4*)&X[(size_t)sidx[wq][e + 2] * kD + lane * 4];
      float4 x3 = *(const float4*)&X[(size_t)sidx[wq][e + 3] * kD + lane * 4];
      a0.x += v0 * x0.x; a0.y += v0 * x0.y; a0.z += v0 * x0.z; a0.w += v0 * x0.w;
      a1.x += v1 * x1.x; a1.y += v1 * x1.y; a1.z += v1 * x1.z; a1.w += v1 * x1.w;
      a2.x += v2 * x2.x; a2.y += v2 * x2.y; a2.z += v2 * x2.z; a2.w += v2 * x2.w;
      a3.x += v3 * x3.x; a3.y += v3 * x3.y; a3.z += v3 * x3.z; a3.w += v3 * x3.w;
    }
    for (; e < cnt; ++e) {
      float v0 = sval[wq][e];
      float4 x0 = *(const float4*)&X[(size_t)sidx[wq][e] * kD + lane * 4];
      a0.x += v0 * x0.x; a0.y += v0 * x0.y; a0.z += v0 * x0.z; a0.w += v0 * x0.w;
    }
    float ax = (a0.x + a1.x) + (a2.x + a3.x);
    float ay = (a0.y + a1.y) + (a2.y + a3.y);
    float az = (a0.z + a1.z) + (a2.z + a3.z);
    float aw4 = (a0.w + a1.w) + (a2.w + a3.w);
    float inv = 1.0f / deg[m];
    ax *= inv; ay *= inv; az *= inv; aw4 *= inv;
    float mean = waveSum(ax + ay + az + aw4) * (1.0f / kD);
    float dx = ax - mean, dy = ay - mean, dz = az - mean, dw = aw4 - mean;
    float var = waveSum(dx * dx + dy * dy + dz * dz + dw * dw) * (1.0f / kD);
    float rstd = rsqrtf(var + kLnEps);
    float4 gv = *(const float4*)&g[lane * 4];
    float4 bv = *(const float4*)&b[lane * 4];
    float o0 = dx * rstd * gv.x + bv.x, o1 = dy * rstd * gv.y + bv.y;
    float o2 = dz * rstd * gv.z + bv.z, o3 = dw * rstd * gv.w + bv.w;
    int off = fragOff(m, lane * 4);
    short4 hi, lo;
    hi.x = f2bf(o0); lo.x = f2bf(o0 - bf2f(hi.x));
    hi.y = f2bf(o1); lo.y = f2bf(o1 - bf2f(hi.y));
    hi.z = f2bf(o2); lo.z = f2bf(o2 - bf2f(hi.z));
    hi.w = f2bf(o3); lo.w = f2bf(o3 - bf2f(hi.w));
    *(short4*)&Enh[off] = hi;
    *(short4*)&Enl[off] = lo;
  } else {
    int row = (bid - 1280) * 4 + wq;
    float4 v = *(const float4*)&X[(size_t)row * kD + lane * 4];
    float s = waveSum(v.x + v.y + v.z + v.w);
    float mean = s * (1.0f / kD);
    float dx = v.x - mean, dy = v.y - mean, dz = v.z - mean, dw = v.w - mean;
    float q = waveSum(dx * dx + dy * dy + dz * dz + dw * dw);
    float rstd = rsqrtf(q * (1.0f / kD) + kLnEps);
    float4 gv = *(const float4*)&g[lane * 4];
    float4 bv = *(const float4*)&b[lane * 4];
    float o0 = dx * rstd * gv.x + bv.x, o1 = dy * rstd * gv.y + bv.y;
    float o2 = dz * rstd * gv.z + bv.z, o3 = dw * rstd * gv.w + bv.w;
    int off = fragOff(row, lane * 4);
    short4 hi, lo;
    hi.x = f2bf(o0); lo.x = f2bf(o0 - bf2f(hi.x));
    hi.y = f2bf(o1); lo.y = f2bf(o1 - bf2f(hi.y));
    hi.z = f2bf(o2); lo.z = f2bf(o2 - bf2f(hi.z));
    hi.w = f2bf(o3); lo.w = f2bf(o3 - bf2f(hi.w));
    *(short4*)&Xnh[off] = hi;
    *(short4*)&Xnl[off] = lo;
  }
}

// ---------------- MFMA GEMM on frag-order inputs ----------------
struct GArg {
  const short* Ah; const short* Al; const short* Wh; const short* Wl;
  const float* bias; float* C; const float* blend;
  short* Ch; short* Cl; int mode;
};
struct FArg {
  const float* part; const float* deg; const float* g; const float* b;
  const float* Wkt_w; const float* Wkt_b; const float* Wks_w; const float* Wks_b;
  float* K;
};

__global__ __launch_bounds__(256) void k_fgemm(GArg a0, GArg a1, FArg f) {
  int t = threadIdx.x;
  if (blockIdx.z == 2) {
    // ---- finktail, 4-way parallel: one block per big-edge column c ----
    if (blockIdx.y != 0 || blockIdx.x >= 4) return;
    int c = blockIdx.x;
    __shared__ float er[kD];
    __shared__ float sh[4];
    float s0 = 0.f, s1 = 0.f, s2 = 0.f, s3 = 0.f;
    float s4 = 0.f, s5 = 0.f, s6 = 0.f, s7 = 0.f;
    const float* pp = f.part + (size_t)c * EB_CHUNKS * kD + t;
#pragma unroll
    for (int k = 0; k < EB_CHUNKS; k += 8) {
      s0 += pp[(k + 0) * kD]; s1 += pp[(k + 1) * kD];
      s2 += pp[(k + 2) * kD]; s3 += pp[(k + 3) * kD];
      s4 += pp[(k + 4) * kD]; s5 += pp[(k + 5) * kD];
      s6 += pp[(k + 6) * kD]; s7 += pp[(k + 7) * kD];
    }
    float s = (((s0 + s1) + (s2 + s3)) + ((s4 + s5) + (s6 + s7))) * (1.0f / f.deg[kN + c]);
    float mean = blockSum256(s, sh) * (1.0f / kD);
    float dv = s - mean;
    float var = blockSum256(dv * dv, sh) * (1.0f / kD);
    er[t] = dv * rsqrtf(var + kLnEps) * f.g[t] + f.b[t];
    __syncthreads();
    const float* W = (c < 3) ? f.Wkt_w : f.Wks_w;
    float acc = 0.f;
    for (int k = 0; k < kD; k += 4) {
      float4 wt = *(const float4*)&W[(size_t)t * kD + k];
      float4 e0 = *(const float4*)&er[k];
      acc += e0.x * wt.x + e0.y * wt.y + e0.z * wt.z + e0.w * wt.w;
    }
    float bt = (c < 3) ? f.Wkt_b[t] : f.Wks_b[t];
    f.K[(size_t)(kN + c) * kD + t] = acc + bt;
    return;
  }
  GArg ga = blockIdx.z ? a1 : a0;
  int wv = t >> 6, lane = t & 63;
  int l15 = lane & 15, sub = lane >> 4;
  int mt = blockIdx.x * 4 + wv;
  int ct0 = blockIdx.y * 4;
  const short* Ah = ga.Ah + mt * 4096;
  const short* Al = ga.Al + mt * 4096;
  v4f acc[4] = {{0,0,0,0},{0,0,0,0},{0,0,0,0},{0,0,0,0}};
#pragma unroll
  for (int kc = 0; kc < 8; ++kc) {
    v8bf ahi = *(const v8bf*)(Ah + kc * 512 + lane * 8);
    v8bf alo = *(const v8bf*)(Al + kc * 512 + lane * 8);
#pragma unroll
    for (int c = 0; c < 4; ++c) {
      int wo = (ct0 + c) * 4096 + kc * 512 + lane * 8;
      v8bf bhi = *(const v8bf*)(ga.Wh + wo);
      v8bf blo = *(const v8bf*)(ga.Wl + wo);
      acc[c] = __builtin_amdgcn_mfma_f32_16x16x32_bf16(ahi, bhi, acc[c], 0, 0, 0);
      acc[c] = __builtin_amdgcn_mfma_f32_16x16x32_bf16(alo, bhi, acc[c], 0, 0, 0);
      acc[c] = __builtin_amdgcn_mfma_f32_16x16x32_bf16(ahi, blo, acc[c], 0, 0, 0);
    }
  }
  int row0 = mt * 16, col0 = blockIdx.y * 64;
#pragma unroll
  for (int c = 0; c < 4; ++c) {
    int col = col0 + c * 16 + l15;
    float bs = ga.bias[col];
#pragma unroll
    for (int r = 0; r < 4; ++r) {
      int row = row0 + sub * 4 + r;
      float v = acc[c][r] + bs;
      if (ga.mode == 1) {
        float x0 = ga.blend[(size_t)row * kD + col];
        v = 0.5f * fmaxf(v, 0.0f) + 0.5f * x0;
      }
      ga.C[(size_t)row * kD + col] = v;
      if (ga.Ch) {
        int off = fragOff(row, col);
        short h = f2bf(v);
        ga.Ch[off] = h;
        ga.Cl[off] = f2bf(v - bf2f(h));
      }
    }
  }
}

// fused a/b projections (frag MFMA) + gate epilogue -> gpart[y][row]
__global__ __launch_bounds__(256) void k_fgemm_ab(
    const short* __restrict__ Ah, const short* __restrict__ Al,
    const short* __restrict__ Wah, const short* __restrict__ Wal,
    const float* __restrict__ ba,
    const short* __restrict__ Wbh, const short* __restrict__ Wbl,
    const float* __restrict__ bbv,
    const float* __restrict__ cw, float* __restrict__ gpart) {
  int t = threadIdx.x;
  int wv = t >> 6, lane = t & 63;
  int l15 = lane & 15, sub = lane >> 4;
  int mt = blockIdx.x * 4 + wv;
  int ct0 = blockIdx.y * 4;
  const short* Ahp = Ah + mt * 4096;
  const short* Alp = Al + mt * 4096;
  v4f acca[4] = {{0,0,0,0},{0,0,0,0},{0,0,0,0},{0,0,0,0}};
  v4f accb[4] = {{0,0,0,0},{0,0,0,0},{0,0,0,0},{0,0,0,0}};
#pragma unroll
  for (int kc = 0; kc < 8; ++kc) {
    v8bf ahi = *(const v8bf*)(Ahp + kc * 512 + lane * 8);
    v8bf alo = *(const v8bf*)(Alp + kc * 512 + lane * 8);
#pragma unroll
    for (int c = 0; c < 4; ++c) {
      int wo = (ct0 + c) * 4096 + kc * 512 + lane * 8;
      v8bf wah = *(const v8bf*)(Wah + wo);
      v8bf wal = *(const v8bf*)(Wal + wo);
      acca[c] = __builtin_amdgcn_mfma_f32_16x16x32_bf16(ahi, wah, acca[c], 0, 0, 0);
      acca[c] = __builtin_amdgcn_mfma_f32_16x16x32_bf16(alo, wah, acca[c], 0, 0, 0);
      acca[c] = __builtin_amdgcn_mfma_f32_16x16x32_bf16(ahi, wal, acca[c], 0, 0, 0);
      v8bf wbh = *(const v8bf*)(Wbh + wo);
      v8bf wbl = *(const v8bf*)(Wbl + wo);
      accb[c] = __builtin_amdgcn_mfma_f32_16x16x32_bf16(ahi, wbh, accb[c], 0, 0, 0);
      accb[c] = __builtin_amdgcn_mfma_f32_16x16x32_bf16(alo, wbh, accb[c], 0, 0, 0);
      accb[c] = __builtin_amdgcn_mfma_f32_16x16x32_bf16(ahi, wbl, accb[c], 0, 0, 0);
    }
  }
  int row0 = mt * 16, col0 = blockIdx.y * 64;
  float rs[4] = {0.f, 0.f, 0.f, 0.f};
#pragma unroll
  for (int c = 0; c < 4; ++c) {
    int col = col0 + c * 16 + l15;
    float bac = ba[col], bbc = bbv[col], cwc = cw[col];
#pragma unroll
    for (int r = 0; r < 4; ++r) {
      float a = tanhf(acca[c][r] + bac);
      float b = 1.0f / (1.0f + __expf(-(accb[c][r] + bbc)));
      rs[r] += a * b * cwc;
    }
  }
#pragma unroll
  for (int r = 0; r < 4; ++r) {
    rs[r] += __shfl_xor(rs[r], 1);
    rs[r] += __shfl_xor(rs[r], 2);
    rs[r] += __shfl_xor(rs[r], 4);
    rs[r] += __shfl_xor(rs[r], 8);
  }
  if (l15 == 0) {
#pragma unroll
    for (int r = 0; r < 4; ++r)
      gpart[(size_t)blockIdx.y * kN + row0 + sub * 4 + r] = rs[r];
  }
}

// sparse masked attention; writes featA in frag order (hi/lo)
__global__ __launch_bounds__(256) void k_attn(
    const float* __restrict__ q, const float* __restrict__ kbuf,
    const int* __restrict__ row_cnt, const int* __restrict__ row_idx,
    short* __restrict__ fAh, short* __restrict__ fAl) {
  __shared__ int sm[ROWCAP];
  __shared__ float qls[kD];
  __shared__ float pls[8][ROWCAP];
  int n = blockIdx.x, t = threadIdx.x;
  int cnt = row_cnt[n];
  if (t < cnt) sm[t] = row_idx[n * ROWCAP + t];
  qls[t] = q[(size_t)n * kD + t];
  __syncthreads();
  int h = t >> 5, j = t & 31;
  float4 qv[8];
#pragma unroll
  for (int d4 = 0; d4 < 8; ++d4) qv[d4] = *(const float4*)&qls[h * 32 + d4 * 4];
  float s1 = 0.f, s2 = 0.f;
  if (j < cnt) {
    const float* kr = &kbuf[(size_t)sm[j] * kD + h * 32];
#pragma unroll
    for (int d4 = 0; d4 < 8; ++d4) {
      float4 kv = *(const float4*)&kr[d4 * 4];
      s1 += qv[d4].x * kv.x + qv[d4].y * kv.y + qv[d4].z * kv.z + qv[d4].w * kv.w;
    }
  }
  if (j + 32 < cnt) {
    const float* kr = &kbuf[(size_t)sm[j + 32] * kD + h * 32];
#pragma unroll
    for (int d4 = 0; d4 < 8; ++d4) {
      float4 kv = *(const float4*)&kr[d4 * 4];
      s2 += qv[d4].x * kv.x + qv[d4].y * kv.y + qv[d4].z * kv.z + qv[d4].w * kv.w;
    }
  }
  s1 *= kScale; s2 *= kScale;
  float v1 = (j < cnt) ? s1 : -3.4e38f;
  float v2 = (j + 32 < cnt) ? s2 : -3.4e38f;
  float mx = fmaxf(v1, v2);
#pragma unroll
  for (int mm = 16; mm >= 1; mm >>= 1) mx = fmaxf(mx, __shfl_xor(mx, mm));
  float p1 = (j < cnt) ? __expf(s1 - mx) : 0.0f;
  float p2 = (j + 32 < cnt) ? __expf(s2 - mx) : 0.0f;
  float ssum = p1 + p2;
#pragma unroll
  for (int mm = 16; mm >= 1; mm >>= 1) ssum += __shfl_xor(ssum, mm);
  float inv = 1.0f / ssum;
  pls[h][j] = p1 * inv;
  pls[h][j + 32] = p2 * inv;
  __syncthreads();
  const float* kb = kbuf + t;
  float ac0 = 0.f, ac1 = 0.f, ac2 = 0.f, ac3 = 0.f;
  int e = 0;
  for (; e + 3 < cnt; e += 4) {
    ac0 += pls[h][e]     * kb[(size_t)sm[e] * kD];
    ac1 += pls[h][e + 1] * kb[(size_t)sm[e + 1] * kD];
    ac2 += pls[h][e + 2] * kb[(size_t)sm[e + 2] * kD];
    ac3 += pls[h][e + 3] * kb[(size_t)sm[e + 3] * kD];
  }
  for (; e < cnt; ++e) ac0 += pls[h][e] * kb[(size_t)sm[e] * kD];
  float v = (ac0 + ac1) + (ac2 + ac3);
  int off = fragOff(n, t);
  short hh = f2bf(v);
  fAh[off] = hh;
  fAl[off] = f2bf(v - bf2f(hh));
}

// ---------------- pooling head ----------------
__global__ __launch_bounds__(256) void k_pool_part(
    const float* __restrict__ gpart, const float* __restrict__ cb,
    const float* __restrict__ feat, float* __restrict__ part) {
  __shared__ float sh[4];
  int b = blockIdx.x, t = threadIdx.x;
  float cb0 = cb[0];
  float mx = -3.4e38f;
  for (int i = t; i < kN; i += 256) {
    float a = gpart[i] + gpart[kN + i] + gpart[2 * kN + i] + gpart[3 * kN + i] + cb0;
    mx = fmaxf(mx, a);
  }
  mx = waveMax(mx);
  int lane = t & 63, w = t >> 6;
  __syncthreads();
  if (lane == 0) sh[w] = mx;
  __syncthreads();
  mx = fmaxf(fmaxf(sh[0], sh[1]), fmaxf(sh[2], sh[3]));
  __syncthreads();
  float s = 0.0f;
  for (int i = t; i < kN; i += 256) {
    float a = gpart[i] + gpart[kN + i] + gpart[2 * kN + i] + gpart[3 * kN + i] + cb0;
    s += expf(a - mx);
  }
  s = blockSum256(s, sh);
  float inv = 1.0f / s;
  float acc = 0.0f;
  for (int r = 0; r < 64; ++r) {
    int n = b * 64 + r;
    float a = gpart[n] + gpart[kN + n] + gpart[2 * kN + n] + gpart[3 * kN + n] + cb0;
    float p = expf(a - mx) * inv;
    acc += p * feat[(size_t)n * kD + t];
  }
  part[(size_t)b * kD + t] = acc;
}

__global__ __launch_bounds__(256) void k_pool_fin(
    const float* __restrict__ part, const float* __restrict__ out_w,
    const float* __restrict__ out_b, float* __restrict__ out) {
  __shared__ float pooled[kD];
  int d = threadIdx.x;
  float s = 0.0f;
#pragma unroll
  for (int b = 0; b < 64; ++b) s += part[(size_t)b * kD + d];
  pooled[d] = s;
  __syncthreads();
  if (d < 4) {
    float o = out_b[d];
    for (int i = 0; i < kD; ++i) o += pooled[i] * out_w[(size_t)d * kD + i];
    out[d] = o;
  }
}

extern "C" void kernel_launch(void* const* d_in, const int* in_sizes, int n_in,
                              void* d_out, int out_size, void* d_ws, size_t ws_size,
                              hipStream_t stream) {
  (void)in_sizes; (void)n_in; (void)out_size; (void)ws_size;
  const float* X     = (const float*)d_in[0];
  const float* H     = (const float*)d_in[1];
  const float* Wq_w  = (const float*)d_in[2];
  const float* Wq_b  = (const float*)d_in[3];
  const float* Wkn_w = (const float*)d_in[4];
  const float* Wkn_b = (const float*)d_in[5];
  const float* Wkt_w = (const float*)d_in[6];
  const float* Wkt_b = (const float*)d_in[7];
  const float* Wks_w = (const float*)d_in[8];
  const float* Wks_b = (const float*)d_in[9];
  const float* fc_w  = (const float*)d_in[10];
  const float* fc_b  = (const float*)d_in[11];
  const float* ln_g  = (const float*)d_in[12];
  const float* ln_b  = (const float*)d_in[13];
  const float* aw    = (const float*)d_in[14];
  const float* ab    = (const float*)d_in[15];
  const float* bw    = (const float*)d_in[16];
  const float* bb    = (const float*)d_in[17];
  const float* cw    = (const float*)d_in[18];
  const float* cb    = (const float*)d_in[19];
  const float* out_w = (const float*)d_in[20];
  const float* out_b = (const float*)d_in[21];

  char* p = (char*)d_ws;
  auto alloc = [&](size_t bytes) -> void* {
    void* r = (void*)p;
    p += (bytes + 255) & ~(size_t)255;
    return r;
  };
  int*   row_cnt = (int*)alloc(kN * 4);
  int*   row_idx = (int*)alloc((size_t)kN * ROWCAP * 4);
  int*   col_cnt = (int*)alloc(kN * 4);
  int*   col_idx = (int*)alloc((size_t)kN * COLCAP * 4);
  float* col_val = (float*)alloc((size_t)kN * COLCAP * 4);
  float* Htail   = (float*)alloc((size_t)4 * kN * 4);
  float* deg     = (float*)alloc(kM * 4);
  float* qbuf    = (float*)alloc((size_t)kN * kD * 4);
  float* kbuf    = (float*)alloc((size_t)kM * kD * 4);
  float* buf0    = (float*)alloc((size_t)kN * kD * 4);
  float* buf1    = (float*)alloc((size_t)kN * kD * 4);
  float* ebpart  = (float*)alloc((size_t)4 * EB_CHUNKS * kD * 4);
  float* gpart   = (float*)alloc((size_t)4 * kN * 4);
  float* ppart   = (float*)alloc(64 * kD * 4);
  short* whi     = (short*)alloc((size_t)8 * 65536 * 2);
  short* wlo     = (short*)alloc((size_t)8 * 65536 * 2);
  short* Xnh     = (short*)alloc((size_t)kN * kD * 2);
  short* Xnl     = (short*)alloc((size_t)kN * kD * 2);
  short* Enh     = (short*)alloc((size_t)kN * kD * 2);
  short* Enl     = (short*)alloc((size_t)kN * kD * 2);
  short* fAh     = (short*)alloc((size_t)kN * kD * 2);
  short* fAl     = (short*)alloc((size_t)kN * kD * 2);
  short* b1h     = (short*)alloc((size_t)kN * kD * 2);
  short* b1l     = (short*)alloc((size_t)kN * kD * 2);

  // wsplit first: also zeroes col_cnt (stream-ordered before build_csr)
  WPtrs wp = {{Wq_w, Wq_w + 65536, Wkn_w, Wkn_w + 65536, fc_w, fc_w + 65536, aw, bw}};
  k_wsplit<<<dim3(256, 8), 256, 0, stream>>>(wp, whi, wlo, col_cnt);
  k_build_csr<<<kN / 4, 256, 0, stream>>>(H, row_cnt, row_idx, col_cnt, col_idx, col_val, Htail);
  k_sort_csc<<<kN / 4, 256, 0, stream>>>(col_cnt, col_idx, col_val, deg);

  FArg fdummy = {};
  GArg gdummy = {};
  for (int layer = 0; layer < 2; ++layer) {
    const float* Xc = layer ? buf0 : X;
    float* Xout = layer ? buf1 : buf0;
    size_t bo = (size_t)layer * kD;
    k_pre<<<2304, 256, 0, stream>>>(Xc, Htail, col_cnt, col_idx, col_val, deg,
                                    ln_g + bo, ln_b + bo, Xnh, Xnl, Enh, Enl,
                                    ebpart, layer == 0);
    GArg qa = {Xnh, Xnl, whi + (size_t)(0 + layer) * 65536, wlo + (size_t)(0 + layer) * 65536,
               Wq_b + bo, qbuf, nullptr, nullptr, nullptr, 0};
    GArg ka = {Enh, Enl, whi + (size_t)(2 + layer) * 65536, wlo + (size_t)(2 + layer) * 65536,
               Wkn_b + bo, kbuf, nullptr, nullptr, nullptr, 0};
    FArg fk = {ebpart, deg, ln_g + bo, ln_b + bo,
               Wkt_w + (size_t)layer * kD * kD, Wkt_b + bo,
               Wks_w + (size_t)layer * kD * kD, Wks_b + bo, kbuf};
    k_fgemm<<<dim3(64, 4, 3), 256, 0, stream>>>(qa, ka, fk);
    k_attn<<<kN, 256, 0, stream>>>(qbuf, kbuf, row_cnt, row_idx, fAh, fAl);
    GArg fa = {fAh, fAl, whi + (size_t)(4 + layer) * 65536, wlo + (size_t)(4 + layer) * 65536,
               fc_b + bo, Xout, Xc, layer ? b1h : nullptr, layer ? b1l : nullptr, 1};
    k_fgemm<<<dim3(64, 4, 1), 256, 0, stream>>>(fa, gdummy, fdummy);
  }

  k_fgemm_ab<<<dim3(64, 4), 256, 0, stream>>>(
      b1h, b1l, whi + (size_t)6 * 65536, wlo + (size_t)6 * 65536, ab,
      whi + (size_t)7 * 65536, wlo + (size_t)7 * 65536, bb, cw, gpart);
  k_pool_part<<<64, 256, 0, stream>>>(gpart, cb, buf1, ppart);
  k_pool_fin<<<1, 256, 0, stream>>>(ppart, out_w, out_b, (float*)d_out);
}

// Round 14
// 215.543 us; speedup vs baseline: 5.4156x; 1.0038x over previous
//
#include <hip/hip_runtime.h>
#include <math.h>

constexpr int kN = 4096;
constexpr int kM = 4100;
constexpr int kD = 256;
constexpr int ROWCAP = 64;
constexpr int COLCAP = 64;
constexpr int EB_CHUNKS = 64;   // 64 chunks x 64 rows per big column
constexpr float kLnEps = 1e-5f;
constexpr float kScale = 0.17677669529663687f; // 1/sqrt(32)

typedef short v8bf __attribute__((ext_vector_type(8)));
typedef float v4f  __attribute__((ext_vector_type(4)));

__device__ __forceinline__ float waveSum(float v) {
#pragma unroll
  for (int m = 32; m >= 1; m >>= 1) v += __shfl_xor(v, m);
  return v;
}
__device__ __forceinline__ float waveMax(float v) {
#pragma unroll
  for (int m = 32; m >= 1; m >>= 1) v = fmaxf(v, __shfl_xor(v, m));
  return v;
}
__device__ __forceinline__ float blockSum256(float v, float* sh) {
  v = waveSum(v);
  int lane = threadIdx.x & 63, w = threadIdx.x >> 6;
  __syncthreads();
  if (lane == 0) sh[w] = v;
  __syncthreads();
  return sh[0] + sh[1] + sh[2] + sh[3];
}

__device__ __forceinline__ short f2bf(float x) {
  unsigned u = __float_as_uint(x);
  unsigned r = (u + 0x7fffu + ((u >> 16) & 1u)) >> 16;
  return (short)r;
}
__device__ __forceinline__ float bf2f(short h) {
  return __uint_as_float(((unsigned)(unsigned short)h) << 16);
}
// fragment-order offset for element (row n, col k) of a [*,256] matrix
__device__ __forceinline__ int fragOff(int n, int k) {
  return ((n >> 4) << 12) + ((k >> 5) << 9) + (((k >> 3) & 3) << 7) + ((n & 15) << 3) + (k & 7);
}

// ---------------- weight presplit (runs FIRST; zeroes col_cnt + done) --------
struct WPtrs { const float* w[8]; };
__global__ __launch_bounds__(256) void k_wsplit(
    WPtrs wp, short* __restrict__ hi, short* __restrict__ lo,
    int* __restrict__ col_cnt, int* __restrict__ done) {
  int mat = blockIdx.y;
  int i = blockIdx.x * 256 + threadIdx.x;   // i = out*256 + k
  if (mat == 0 && blockIdx.x < 16) col_cnt[blockIdx.x * 256 + threadIdx.x] = 0;
  if (mat == 0 && blockIdx.x == 16 && threadIdx.x == 0) *done = 0;
  int out = i >> 8, k = i & 255;
  float v = wp.w[mat][i];
  short h = f2bf(v);
  size_t base = (size_t)mat * 65536 + fragOff(out, k);
  hi[base] = h;
  lo[base] = f2bf(v - bf2f(h));
}

// ---------------- sparse build ----------------
__global__ __launch_bounds__(256) void k_build_csr(
    const float* __restrict__ H, int* __restrict__ row_cnt, int* __restrict__ row_idx,
    int* __restrict__ col_cnt, int* __restrict__ col_idx, float* __restrict__ col_val,
    float* __restrict__ Htail) {
  int n = (blockIdx.x * blockDim.x + threadIdx.x) >> 6;
  int lane = threadIdx.x & 63;
  const float* hrow = H + (size_t)n * kM;
  float4 v[16];
#pragma unroll
  for (int c = 0; c < 16; ++c) v[c] = *(const float4*)&hrow[c * 256 + lane * 4];
  float tv = (lane < 4) ? hrow[4096 + lane] : 0.0f;
  if (lane < 4) Htail[lane * kN + n] = tv;
  unsigned long long below = (1ull << lane) - 1ull;
  int cnt = 0;
#pragma unroll
  for (int c = 0; c < 16; ++c) {
    int mbase = c * 256 + lane * 4;
    float vv[4] = {v[c].x, v[c].y, v[c].z, v[c].w};
    unsigned long long bal[4];
#pragma unroll
    for (int j = 0; j < 4; ++j) bal[j] = __ballot(vv[j] != 0.0f);
    int pre = 0, tot = 0;
#pragma unroll
    for (int j = 0; j < 4; ++j) { pre += __popcll(bal[j] & below); tot += __popcll(bal[j]); }
    int local = 0;
#pragma unroll
    for (int j = 0; j < 4; ++j) {
      if (vv[j] != 0.0f) {
        int m = mbase + j;
        int pos = cnt + pre + local;
        if (pos < ROWCAP) row_idx[n * ROWCAP + pos] = m;
        int pc = atomicAdd(&col_cnt[m], 1);
        if (pc < COLCAP) { col_idx[m * COLCAP + pc] = n; col_val[m * COLCAP + pc] = vv[j]; }
        local++;
      }
    }
    cnt += tot;
  }
  unsigned long long bal = __ballot(tv != 0.0f);
  if (tv != 0.0f) {
    int pos = cnt + __popcll(bal & below);
    if (pos < ROWCAP) row_idx[n * ROWCAP + pos] = 4096 + lane;
  }
  cnt += __popcll(bal);
  if (lane == 0) row_cnt[n] = cnt < ROWCAP ? cnt : ROWCAP;
}

// ---------------- fused per-layer pre-pass ----------------
// blocks [0,256): big-column 64-row chunk partial sums + deg partials
// blocks [256,1280): E rows (in-wave-sorted CSC gather + LN) -> En frags
// blocks [1280,2304): LN(X) -> Xn frags
__global__ __launch_bounds__(256) void k_pre(
    const float* __restrict__ X, const float* __restrict__ Htail,
    const int* __restrict__ col_cnt, const int* __restrict__ col_idx,
    const float* __restrict__ col_val,
    const float* __restrict__ g, const float* __restrict__ b,
    short* __restrict__ Xnh, short* __restrict__ Xnl,
    short* __restrict__ Enh, short* __restrict__ Enl,
    float* __restrict__ ebpart, float* __restrict__ deg_part) {
  __shared__ int sidx[4][COLCAP];
  __shared__ float sval[4][COLCAP];
  int bid = blockIdx.x, t = threadIdx.x;
  int wq = t >> 6, lane = t & 63;
  if (bid < 256) {
    __shared__ float hv[64];
    int c = bid >> 6, chunk = bid & 63;
    int r0 = chunk * 64;
    if (t < 64) {
      float hvv = Htail[c * kN + r0 + t];
      hv[t] = hvv;
      float ds = waveSum(hvv);   // values in {0,1}: integer-exact partial
      if (t == 0) deg_part[c * 64 + chunk] = ds;
    }
    __syncthreads();
    float s0 = 0.f, s1 = 0.f, s2 = 0.f, s3 = 0.f;
#pragma unroll
    for (int i = 0; i < 64; i += 4) {
      s0 += hv[i]     * X[(size_t)(r0 + i) * kD + t];
      s1 += hv[i + 1] * X[(size_t)(r0 + i + 1) * kD + t];
      s2 += hv[i + 2] * X[(size_t)(r0 + i + 2) * kD + t];
      s3 += hv[i + 3] * X[(size_t)(r0 + i + 3) * kD + t];
    }
    ebpart[(size_t)(c * EB_CHUNKS + chunk) * kD + t] = ((s0 + s1) + (s2 + s3));
  } else if (bid < 1280) {
    // ---- E row: load unsorted CSC entries, in-wave sort by index ----
    int m = (bid - 256) * 4 + wq;
    int cnt = col_cnt[m]; if (cnt > COLCAP) cnt = COLCAP;
    int iv = 0x7fffffff; float vvl = 0.0f;
    if (lane < cnt) { iv = col_idx[m * COLCAP + lane]; vvl = col_val[m * COLCAP + lane]; }
    float dsum = waveSum(vvl);   // deg: {1,2} values, integer-exact any order
    int rank = 0;
    for (int j = 0; j < 64; ++j) {
      int ivj = __shfl(iv, j);
      if (ivj < iv) rank++;
    }
    if (lane < cnt) { sidx[wq][rank] = iv; sval[wq][rank] = vvl; }
    __syncthreads();
    float4 a0 = {0,0,0,0}, a1 = {0,0,0,0}, a2 = {0,0,0,0}, a3 = {0,0,0,0};
    int e = 0;
    for (; e + 3 < cnt; e += 4) {
      float v0 = sval[wq][e],     v1 = sval[wq][e + 1];
      float v2 = sval[wq][e + 2], v3 = sval[wq][e + 3];
      float4 x0 = *(const float4*)&X[(size_t)sidx[wq][e] * kD + lane * 4];
      float4 x1 = *(const float4*)&X[(size_t)sidx[wq][e + 1] * kD + lane * 4];
      float4 x2 = *(const float4*)&X[(size_t)sidx[wq][e + 2] * kD + lane * 4];
      float4 x3 = *(const float4*)&X[(size_t)sidx[wq][e + 3] * kD + lane * 4];
      a0.x += v0 * x0.x; a0.y += v0 * x0.y; a0.z += v0 * x0.z; a0.w += v0 * x0.w;
      a1.x += v1 * x1.x; a1.y += v1 * x1.y; a1.z += v1 * x1.z; a1.w += v1 * x1.w;
      a2.x += v2 * x2.x; a2.y += v2 * x2.y; a2.z += v2 * x2.z; a2.w += v2 * x2.w;
      a3.x += v3 * x3.x; a3.y += v3 * x3.y; a3.z += v3 * x3.z; a3.w += v3 * x3.w;
    }
    for (; e < cnt; ++e) {
      float v0 = sval[wq][e];
      float4 x0 = *(const float4*)&X[(size_t)sidx[wq][e] * kD + lane * 4];
      a0.x += v0 * x0.x; a0.y += v0 * x0.y; a0.z += v0 * x0.z; a0.w += v0 * x0.w;
    }
    float ax = (a0.x + a1.x) + (a2.x + a3.x);
    float ay = (a0.y + a1.y) + (a2.y + a3.y);
    float az = (a0.z + a1.z) + (a2.z + a3.z);
    float aw4 = (a0.w + a1.w) + (a2.w + a3.w);
    float inv = 1.0f / dsum;
    ax *= inv; ay *= inv; az *= inv; aw4 *= inv;
    float mean = waveSum(ax + ay + az + aw4) * (1.0f / kD);
    float dx = ax - mean, dy = ay - mean, dz = az - mean, dw = aw4 - mean;
    float var = waveSum(dx * dx + dy * dy + dz * dz + dw * dw) * (1.0f / kD);
    float rstd = rsqrtf(var + kLnEps);
    float4 gv = *(const float4*)&g[lane * 4];
    float4 bv = *(const float4*)&b[lane * 4];
    float o0 = dx * rstd * gv.x + bv.x, o1 = dy * rstd * gv.y + bv.y;
    float o2 = dz * rstd * gv.z + bv.z, o3 = dw * rstd * gv.w + bv.w;
    int off = fragOff(m, lane * 4);
    short4 hi, lo;
    hi.x = f2bf(o0); lo.x = f2bf(o0 - bf2f(hi.x));
    hi.y = f2bf(o1); lo.y = f2bf(o1 - bf2f(hi.y));
    hi.z = f2bf(o2); lo.z = f2bf(o2 - bf2f(hi.z));
    hi.w = f2bf(o3); lo.w = f2bf(o3 - bf2f(hi.w));
    *(short4*)&Enh[off] = hi;
    *(short4*)&Enl[off] = lo;
  } else {
    int row = (bid - 1280) * 4 + wq;
    float4 v = *(const float4*)&X[(size_t)row * kD + lane * 4];
    float s = waveSum(v.x + v.y + v.z + v.w);
    float mean = s * (1.0f / kD);
    float dx = v.x - mean, dy = v.y - mean, dz = v.z - mean, dw = v.w - mean;
    float q = waveSum(dx * dx + dy * dy + dz * dz + dw * dw);
    float rstd = rsqrtf(q * (1.0f / kD) + kLnEps);
    float4 gv = *(const float4*)&g[lane * 4];
    float4 bv = *(const float4*)&b[lane * 4];
    float o0 = dx * rstd * gv.x + bv.x, o1 = dy * rstd * gv.y + bv.y;
    float o2 = dz * rstd * gv.z + bv.z, o3 = dw * rstd * gv.w + bv.w;
    int off = fragOff(row, lane * 4);
    short4 hi, lo;
    hi.x = f2bf(o0); lo.x = f2bf(o0 - bf2f(hi.x));
    hi.y = f2bf(o1); lo.y = f2bf(o1 - bf2f(hi.y));
    hi.z = f2bf(o2); lo.z = f2bf(o2 - bf2f(hi.z));
    hi.w = f2bf(o3); lo.w = f2bf(o3 - bf2f(hi.w));
    *(short4*)&Xnh[off] = hi;
    *(short4*)&Xnl[off] = lo;
  }
}

// ---------------- MFMA GEMM on frag-order inputs ----------------
struct GArg {
  const short* Ah; const short* Al; const short* Wh; const short* Wl;
  const float* bias; float* C; const float* blend;
  short* Ch; short* Cl; int mode;
};
struct FArg {
  const float* part; const float* deg_part; const float* g; const float* b;
  const float* Wkt_w; const float* Wkt_b; const float* Wks_w; const float* Wks_b;
  float* K;
};

__global__ __launch_bounds__(256) void k_fgemm(GArg a0, GArg a1, FArg f) {
  int t = threadIdx.x;
  if (blockIdx.z == 2) {
    // ---- finktail, 4-way parallel: one block per big-edge column c ----
    if (blockIdx.y != 0 || blockIdx.x >= 4) return;
    int c = blockIdx.x;
    __shared__ float er[kD];
    __shared__ float sh[4];
    float degsum = 0.f;
    const float* dp = f.deg_part + c * 64;
#pragma unroll
    for (int k = 0; k < 64; ++k) degsum += dp[k];   // {0,1} counts: exact
    float s0 = 0.f, s1 = 0.f, s2 = 0.f, s3 = 0.f;
    float s4 = 0.f, s5 = 0.f, s6 = 0.f, s7 = 0.f;
    const float* pp = f.part + (size_t)c * EB_CHUNKS * kD + t;
#pragma unroll
    for (int k = 0; k < EB_CHUNKS; k += 8) {
      s0 += pp[(k + 0) * kD]; s1 += pp[(k + 1) * kD];
      s2 += pp[(k + 2) * kD]; s3 += pp[(k + 3) * kD];
      s4 += pp[(k + 4) * kD]; s5 += pp[(k + 5) * kD];
      s6 += pp[(k + 6) * kD]; s7 += pp[(k + 7) * kD];
    }
    float s = (((s0 + s1) + (s2 + s3)) + ((s4 + s5) + (s6 + s7))) * (1.0f / degsum);
    float mean = blockSum256(s, sh) * (1.0f / kD);
    float dv = s - mean;
    float var = blockSum256(dv * dv, sh) * (1.0f / kD);
    er[t] = dv * rsqrtf(var + kLnEps) * f.g[t] + f.b[t];
    __syncthreads();
    const float* W = (c < 3) ? f.Wkt_w : f.Wks_w;
    float acc = 0.f;
    for (int k = 0; k < kD; k += 4) {
      float4 wt = *(const float4*)&W[(size_t)t * kD + k];
      float4 e0 = *(const float4*)&er[k];
      acc += e0.x * wt.x + e0.y * wt.y + e0.z * wt.z + e0.w * wt.w;
    }
    float bt = (c < 3) ? f.Wkt_b[t] : f.Wks_b[t];
    f.K[(size_t)(kN + c) * kD + t] = acc + bt;
    return;
  }
  GArg ga = blockIdx.z ? a1 : a0;
  int wv = t >> 6, lane = t & 63;
  int l15 = lane & 15, sub = lane >> 4;
  int mt = blockIdx.x * 4 + wv;
  int ct0 = blockIdx.y * 4;
  const short* Ah = ga.Ah + mt * 4096;
  const short* Al = ga.Al + mt * 4096;
  v4f acc[4] = {{0,0,0,0},{0,0,0,0},{0,0,0,0},{0,0,0,0}};
#pragma unroll
  for (int kc = 0; kc < 8; ++kc) {
    v8bf ahi = *(const v8bf*)(Ah + kc * 512 + lane * 8);
    v8bf alo = *(const v8bf*)(Al + kc * 512 + lane * 8);
#pragma unroll
    for (int c = 0; c < 4; ++c) {
      int wo = (ct0 + c) * 4096 + kc * 512 + lane * 8;
      v8bf bhi = *(const v8bf*)(ga.Wh + wo);
      v8bf blo = *(const v8bf*)(ga.Wl + wo);
      acc[c] = __builtin_amdgcn_mfma_f32_16x16x32_bf16(ahi, bhi, acc[c], 0, 0, 0);
      acc[c] = __builtin_amdgcn_mfma_f32_16x16x32_bf16(alo, bhi, acc[c], 0, 0, 0);
      acc[c] = __builtin_amdgcn_mfma_f32_16x16x32_bf16(ahi, blo, acc[c], 0, 0, 0);
    }
  }
  int row0 = mt * 16, col0 = blockIdx.y * 64;
#pragma unroll
  for (int c = 0; c < 4; ++c) {
    int col = col0 + c * 16 + l15;
    float bs = ga.bias[col];
#pragma unroll
    for (int r = 0; r < 4; ++r) {
      int row = row0 + sub * 4 + r;
      float v = acc[c][r] + bs;
      if (ga.mode == 1) {
        float x0 = ga.blend[(size_t)row * kD + col];
        v = 0.5f * fmaxf(v, 0.0f) + 0.5f * x0;
      }
      ga.C[(size_t)row * kD + col] = v;
      if (ga.Ch) {
        int off = fragOff(row, col);
        short h = f2bf(v);
        ga.Ch[off] = h;
        ga.Cl[off] = f2bf(v - bf2f(h));
      }
    }
  }
}

// fused a/b projections (frag MFMA) + gate epilogue -> gpart[y][row]
__global__ __launch_bounds__(256) void k_fgemm_ab(
    const short* __restrict__ Ah, const short* __restrict__ Al,
    const short* __restrict__ Wah, const short* __restrict__ Wal,
    const float* __restrict__ ba,
    const short* __restrict__ Wbh, const short* __restrict__ Wbl,
    const float* __restrict__ bbv,
    const float* __restrict__ cw, float* __restrict__ gpart) {
  int t = threadIdx.x;
  int wv = t >> 6, lane = t & 63;
  int l15 = lane & 15, sub = lane >> 4;
  int mt = blockIdx.x * 4 + wv;
  int ct0 = blockIdx.y * 4;
  const short* Ahp = Ah + mt * 4096;
  const short* Alp = Al + mt * 4096;
  v4f acca[4] = {{0,0,0,0},{0,0,0,0},{0,0,0,0},{0,0,0,0}};
  v4f accb[4] = {{0,0,0,0},{0,0,0,0},{0,0,0,0},{0,0,0,0}};
#pragma unroll
  for (int kc = 0; kc < 8; ++kc) {
    v8bf ahi = *(const v8bf*)(Ahp + kc * 512 + lane * 8);
    v8bf alo = *(const v8bf*)(Alp + kc * 512 + lane * 8);
#pragma unroll
    for (int c = 0; c < 4; ++c) {
      int wo = (ct0 + c) * 4096 + kc * 512 + lane * 8;
      v8bf wah = *(const v8bf*)(Wah + wo);
      v8bf wal = *(const v8bf*)(Wal + wo);
      acca[c] = __builtin_amdgcn_mfma_f32_16x16x32_bf16(ahi, wah, acca[c], 0, 0, 0);
      acca[c] = __builtin_amdgcn_mfma_f32_16x16x32_bf16(alo, wah, acca[c], 0, 0, 0);
      acca[c] = __builtin_amdgcn_mfma_f32_16x16x32_bf16(ahi, wal, acca[c], 0, 0, 0);
      v8bf wbh = *(const v8bf*)(Wbh + wo);
      v8bf wbl = *(const v8bf*)(Wbl + wo);
      accb[c] = __builtin_amdgcn_mfma_f32_16x16x32_bf16(ahi, wbh, accb[c], 0, 0, 0);
      accb[c] = __builtin_amdgcn_mfma_f32_16x16x32_bf16(alo, wbh, accb[c], 0, 0, 0);
      accb[c] = __builtin_amdgcn_mfma_f32_16x16x32_bf16(ahi, wbl, accb[c], 0, 0, 0);
    }
  }
  int row0 = mt * 16, col0 = blockIdx.y * 64;
  float rs[4] = {0.f, 0.f, 0.f, 0.f};
#pragma unroll
  for (int c = 0; c < 4; ++c) {
    int col = col0 + c * 16 + l15;
    float bac = ba[col], bbc = bbv[col], cwc = cw[col];
#pragma unroll
    for (int r = 0; r < 4; ++r) {
      float a = tanhf(acca[c][r] + bac);
      float b = 1.0f / (1.0f + __expf(-(accb[c][r] + bbc)));
      rs[r] += a * b * cwc;
    }
  }
#pragma unroll
  for (int r = 0; r < 4; ++r) {
    rs[r] += __shfl_xor(rs[r], 1);
    rs[r] += __shfl_xor(rs[r], 2);
    rs[r] += __shfl_xor(rs[r], 4);
    rs[r] += __shfl_xor(rs[r], 8);
  }
  if (l15 == 0) {
#pragma unroll
    for (int r = 0; r < 4; ++r)
      gpart[(size_t)blockIdx.y * kN + row0 + sub * 4 + r] = rs[r];
  }
}

// sparse masked attention; writes featA in frag order (hi/lo)
__global__ __launch_bounds__(256) void k_attn(
    const float* __restrict__ q, const float* __restrict__ kbuf,
    const int* __restrict__ row_cnt, const int* __restrict__ row_idx,
    short* __restrict__ fAh, short* __restrict__ fAl) {
  __shared__ int sm[ROWCAP];
  __shared__ float qls[kD];
  __shared__ float pls[8][ROWCAP];
  int n = blockIdx.x, t = threadIdx.x;
  int cnt = row_cnt[n];
  if (t < cnt) sm[t] = row_idx[n * ROWCAP + t];
  qls[t] = q[(size_t)n * kD + t];
  __syncthreads();
  int h = t >> 5, j = t & 31;
  float4 qv[8];
#pragma unroll
  for (int d4 = 0; d4 < 8; ++d4) qv[d4] = *(const float4*)&qls[h * 32 + d4 * 4];
  float s1 = 0.f, s2 = 0.f;
  if (j < cnt) {
    const float* kr = &kbuf[(size_t)sm[j] * kD + h * 32];
#pragma unroll
    for (int d4 = 0; d4 < 8; ++d4) {
      float4 kv = *(const float4*)&kr[d4 * 4];
      s1 += qv[d4].x * kv.x + qv[d4].y * kv.y + qv[d4].z * kv.z + qv[d4].w * kv.w;
    }
  }
  if (j + 32 < cnt) {
    const float* kr = &kbuf[(size_t)sm[j + 32] * kD + h * 32];
#pragma unroll
    for (int d4 = 0; d4 < 8; ++d4) {
      float4 kv = *(const float4*)&kr[d4 * 4];
      s2 += qv[d4].x * kv.x + qv[d4].y * kv.y + qv[d4].z * kv.z + qv[d4].w * kv.w;
    }
  }
  s1 *= kScale; s2 *= kScale;
  float v1 = (j < cnt) ? s1 : -3.4e38f;
  float v2 = (j + 32 < cnt) ? s2 : -3.4e38f;
  float mx = fmaxf(v1, v2);
#pragma unroll
  for (int mm = 16; mm >= 1; mm >>= 1) mx = fmaxf(mx, __shfl_xor(mx, mm));
  float p1 = (j < cnt) ? __expf(s1 - mx) : 0.0f;
  float p2 = (j + 32 < cnt) ? __expf(s2 - mx) : 0.0f;
  float ssum = p1 + p2;
#pragma unroll
  for (int mm = 16; mm >= 1; mm >>= 1) ssum += __shfl_xor(ssum, mm);
  float inv = 1.0f / ssum;
  pls[h][j] = p1 * inv;
  pls[h][j + 32] = p2 * inv;
  __syncthreads();
  const float* kb = kbuf + t;
  float ac0 = 0.f, ac1 = 0.f, ac2 = 0.f, ac3 = 0.f;
  int e = 0;
  for (; e + 3 < cnt; e += 4) {
    ac0 += pls[h][e]     * kb[(size_t)sm[e] * kD];
    ac1 += pls[h][e + 1] * kb[(size_t)sm[e + 1] * kD];
    ac2 += pls[h][e + 2] * kb[(size_t)sm[e + 2] * kD];
    ac3 += pls[h][e + 3] * kb[(size_t)sm[e + 3] * kD];
  }
  for (; e < cnt; ++e) ac0 += pls[h][e] * kb[(size_t)sm[e] * kD];
  float v = (ac0 + ac1) + (ac2 + ac3);
  int off = fragOff(n, t);
  short hh = f2bf(v);
  fAh[off] = hh;
  fAl[off] = f2bf(v - bf2f(hh));
}

// ---------------- fused pooling (partials + last-block finish) ----------------
__global__ __launch_bounds__(256) void k_pool(
    const float* __restrict__ gpart, const float* __restrict__ cb,
    const float* __restrict__ feat, float* __restrict__ part,
    const float* __restrict__ out_w, const float* __restrict__ out_b,
    float* __restrict__ out, int* __restrict__ done) {
  __shared__ float sh[4];
  __shared__ float pooled[kD];
  __shared__ int lastFlag;
  int b = blockIdx.x, t = threadIdx.x;
  float cb0 = cb[0];
  float mx = -3.4e38f;
  for (int i = t; i < kN; i += 256) {
    float a = gpart[i] + gpart[kN + i] + gpart[2 * kN + i] + gpart[3 * kN + i] + cb0;
    mx = fmaxf(mx, a);
  }
  mx = waveMax(mx);
  int lane = t & 63, w = t >> 6;
  __syncthreads();
  if (lane == 0) sh[w] = mx;
  __syncthreads();
  mx = fmaxf(fmaxf(sh[0], sh[1]), fmaxf(sh[2], sh[3]));
  __syncthreads();
  float s = 0.0f;
  for (int i = t; i < kN; i += 256) {
    float a = gpart[i] + gpart[kN + i] + gpart[2 * kN + i] + gpart[3 * kN + i] + cb0;
    s += expf(a - mx);
  }
  s = blockSum256(s, sh);
  float inv = 1.0f / s;
  float acc = 0.0f;
  for (int r = 0; r < 64; ++r) {
    int n = b * 64 + r;
    float a = gpart[n] + gpart[kN + n] + gpart[2 * kN + n] + gpart[3 * kN + n] + cb0;
    float p = expf(a - mx) * inv;
    acc += p * feat[(size_t)n * kD + t];
  }
  part[(size_t)b * kD + t] = acc;
  // last block finishes (fixed read order -> deterministic)
  __threadfence();
  if (t == 0) {
    int old = atomicAdd(done, 1);
    lastFlag = (old == 63) ? 1 : 0;
  }
  __syncthreads();
  if (lastFlag) {
    __threadfence();
    float s2 = 0.0f;
#pragma unroll
    for (int q = 0; q < 64; ++q) s2 += part[(size_t)q * kD + t];
    pooled[t] = s2;
    __syncthreads();
    if (t < 4) {
      float o = out_b[t];
      for (int i = 0; i < kD; ++i) o += pooled[i] * out_w[(size_t)t * kD + i];
      out[t] = o;
    }
  }
}

extern "C" void kernel_launch(void* const* d_in, const int* in_sizes, int n_in,
                              void* d_out, int out_size, void* d_ws, size_t ws_size,
                              hipStream_t stream) {
  (void)in_sizes; (void)n_in; (void)out_size; (void)ws_size;
  const float* X     = (const float*)d_in[0];
  const float* H     = (const float*)d_in[1];
  const float* Wq_w  = (const float*)d_in[2];
  const float* Wq_b  = (const float*)d_in[3];
  const float* Wkn_w = (const float*)d_in[4];
  const float* Wkn_b = (const float*)d_in[5];
  const float* Wkt_w = (const float*)d_in[6];
  const float* Wkt_b = (const float*)d_in[7];
  const float* Wks_w = (const float*)d_in[8];
  const float* Wks_b = (const float*)d_in[9];
  const float* fc_w  = (const float*)d_in[10];
  const float* fc_b  = (const float*)d_in[11];
  const float* ln_g  = (const float*)d_in[12];
  const float* ln_b  = (const float*)d_in[13];
  const float* aw    = (const float*)d_in[14];
  const float* ab    = (const float*)d_in[15];
  const float* bw    = (const float*)d_in[16];
  const float* bb    = (const float*)d_in[17];
  const float* cw    = (const float*)d_in[18];
  const float* cb    = (const float*)d_in[19];
  const float* out_w = (const float*)d_in[20];
  const float* out_b = (const float*)d_in[21];

  char* p = (char*)d_ws;
  auto alloc = [&](size_t bytes) -> void* {
    void* r = (void*)p;
    p += (bytes + 255) & ~(size_t)255;
    return r;
  };
  int*   row_cnt  = (int*)alloc(kN * 4);
  int*   row_idx  = (int*)alloc((size_t)kN * ROWCAP * 4);
  int*   col_cnt  = (int*)alloc(kN * 4);
  int*   col_idx  = (int*)alloc((size_t)kN * COLCAP * 4);
  float* col_val  = (float*)alloc((size_t)kN * COLCAP * 4);
  float* Htail    = (float*)alloc((size_t)4 * kN * 4);
  float* deg_part = (float*)alloc(4 * 64 * 4);
  int*   done     = (int*)alloc(256);
  float* qbuf     = (float*)alloc((size_t)kN * kD * 4);
  float* kbuf     = (float*)alloc((size_t)kM * kD * 4);
  float* buf0     = (float*)alloc((size_t)kN * kD * 4);
  float* buf1     = (float*)alloc((size_t)kN * kD * 4);
  float* ebpart   = (float*)alloc((size_t)4 * EB_CHUNKS * kD * 4);
  float* gpart    = (float*)alloc((size_t)4 * kN * 4);
  float* ppart    = (float*)alloc(64 * kD * 4);
  short* whi      = (short*)alloc((size_t)8 * 65536 * 2);
  short* wlo      = (short*)alloc((size_t)8 * 65536 * 2);
  short* Xnh      = (short*)alloc((size_t)kN * kD * 2);
  short* Xnl      = (short*)alloc((size_t)kN * kD * 2);
  short* Enh      = (short*)alloc((size_t)kN * kD * 2);
  short* Enl      = (short*)alloc((size_t)kN * kD * 2);
  short* fAh      = (short*)alloc((size_t)kN * kD * 2);
  short* fAl      = (short*)alloc((size_t)kN * kD * 2);
  short* b1h      = (short*)alloc((size_t)kN * kD * 2);
  short* b1l      = (short*)alloc((size_t)kN * kD * 2);

  // wsplit first: zeroes col_cnt + done (stream-ordered before build_csr/pool)
  WPtrs wp = {{Wq_w, Wq_w + 65536, Wkn_w, Wkn_w + 65536, fc_w, fc_w + 65536, aw, bw}};
  k_wsplit<<<dim3(256, 8), 256, 0, stream>>>(wp, whi, wlo, col_cnt, done);
  k_build_csr<<<kN / 4, 256, 0, stream>>>(H, row_cnt, row_idx, col_cnt, col_idx, col_val, Htail);

  FArg fdummy = {};
  GArg gdummy = {};
  for (int layer = 0; layer < 2; ++layer) {
    const float* Xc = layer ? buf0 : X;
    float* Xout = layer ? buf1 : buf0;
    size_t bo = (size_t)layer * kD;
    k_pre<<<2304, 256, 0, stream>>>(Xc, Htail, col_cnt, col_idx, col_val,
                                    ln_g + bo, ln_b + bo, Xnh, Xnl, Enh, Enl,
                                    ebpart, deg_part);
    GArg qa = {Xnh, Xnl, whi + (size_t)(0 + layer) * 65536, wlo + (size_t)(0 + layer) * 65536,
               Wq_b + bo, qbuf, nullptr, nullptr, nullptr, 0};
    GArg ka = {Enh, Enl, whi + (size_t)(2 + layer) * 65536, wlo + (size_t)(2 + layer) * 65536,
               Wkn_b + bo, kbuf, nullptr, nullptr, nullptr, 0};
    FArg fk = {ebpart, deg_part, ln_g + bo, ln_b + bo,
               Wkt_w + (size_t)layer * kD * kD, Wkt_b + bo,
               Wks_w + (size_t)layer * kD * kD, Wks_b + bo, kbuf};
    k_fgemm<<<dim3(64, 4, 3), 256, 0, stream>>>(qa, ka, fk);
    k_attn<<<kN, 256, 0, stream>>>(qbuf, kbuf, row_cnt, row_idx, fAh, fAl);
    GArg fa = {fAh, fAl, whi + (size_t)(4 + layer) * 65536, wlo + (size_t)(4 + layer) * 65536,
               fc_b + bo, Xout, Xc, layer ? b1h : nullptr, layer ? b1l : nullptr, 1};
    k_fgemm<<<dim3(64, 4, 1), 256, 0, stream>>>(fa, gdummy, fdummy);
  }

  k_fgemm_ab<<<dim3(64, 4), 256, 0, stream>>>(
      b1h, b1l, whi + (size_t)6 * 65536, wlo + (size_t)6 * 65536, ab,
      whi + (size_t)7 * 65536, wlo + (size_t)7 * 65536, bb, cw, gpart);
  k_pool<<<64, 256, 0, stream>>>(gpart, cb, buf1, ppart, out_w, out_b,
                                 (float*)d_out, done);
}